// Round 2
// baseline (3412.114 us; speedup 1.0000x reference)
//
#include <hip/hip_runtime.h>

typedef unsigned short u16;
typedef __attribute__((ext_vector_type(8))) short short8;
typedef __attribute__((ext_vector_type(4))) float f32x4;

__device__ __forceinline__ u16 f2b(float f){
    unsigned u = __builtin_bit_cast(unsigned, f);
    u += 0x7fffu + ((u >> 16) & 1u);   // RNE
    return (u16)(u >> 16);
}
__device__ __forceinline__ float b2f(u16 s){
    unsigned u = ((unsigned)s) << 16;
    return __builtin_bit_cast(float, u);
}
__device__ __forceinline__ float sigm(float x){ return 1.f/(1.f + __expf(-x)); }
// branch-free tanh: 1 - 2/(1+e^{2x});  x->+inf: e=inf -> 1; x->-inf: e=0 -> -1
__device__ __forceinline__ float tanhf2(float x){
    float e = __expf(2.f * x);
    return 1.f - 2.f/(1.f + e);
}

// ---------------- fp32 -> bf16 conversion ----------------
__global__ __launch_bounds__(256) void cvt_bf16(const float* __restrict__ s,
                                                u16* __restrict__ d, int n4){
    int i = blockIdx.x*256 + threadIdx.x;
    if (i < n4){
        float4 v = ((const float4*)s)[i];
        ushort4 o;
        o.x = f2b(v.x); o.y = f2b(v.y); o.z = f2b(v.z); o.w = f2b(v.w);
        ((ushort4*)d)[i] = o;
    }
}

// ---- W_ih cvt with row permutation: out row (unit*4+gate) = in row (gate*128+unit) ----
__global__ __launch_bounds__(192) void cvt_wih_perm(const float* __restrict__ s,
                                                    u16* __restrict__ d){
    int r = blockIdx.x;               // 0..511 input row
    int j = threadIdx.x;              // 0..191 float4 within row
    int g = r >> 7, u = r & 127;
    int ro = u * 4 + g;
    float4 v = ((const float4*)(s + (size_t)r * 768))[j];
    ushort4 o;
    o.x = f2b(v.x); o.y = f2b(v.y); o.z = f2b(v.z); o.w = f2b(v.w);
    ((ushort4*)(d + (size_t)ro * 768))[j] = o;
}

// ---- W_hh cvt with the same row permutation, 128 cols, bf16 out ----
__global__ __launch_bounds__(256) void cvt_whh_perm(const float* __restrict__ s,
                                                    u16* __restrict__ d){
    int idx = blockIdx.x*256 + threadIdx.x;   // 0..16383
    if (idx >= 512*32) return;
    int r = idx >> 5, j = idx & 31;           // row, float4 within row
    int g = r >> 7, u = r & 127;
    int ro = u * 4 + g;
    float4 v = ((const float4*)(s + (size_t)r * 128))[j];
    ushort4 o;
    o.x = f2b(v.x); o.y = f2b(v.y); o.z = f2b(v.z); o.w = f2b(v.w);
    ((ushort4*)(d + (size_t)ro * 128))[j] = o;
}

// ---------------- embedding-gather + input projection GEMM ----------------
// pre[m, n] = sum_k E[tok[m], k] * Wt[n, k] + bias(n);  M x 1024, K=768
// Wt rows (and hence pre cols) are PERMUTED: within each 512-half, p = unit*4+gate.
__global__ __launch_bounds__(256) void gemm_embed(
    const u16* __restrict__ E, const int* __restrict__ tok,
    const u16* __restrict__ Wt, const float* __restrict__ bf_,
    const float* __restrict__ bb_, u16* __restrict__ pre)
{
    __shared__ __align__(16) u16 Asm[128*32];
    __shared__ __align__(16) u16 Bsm[128*32];
    const int m0 = blockIdx.x * 128, n0 = blockIdx.y * 128;
    const int tid = threadIdx.x;
    const int ar = tid >> 2, ch = (tid & 3) * 8;
    const u16* ap0 = E + (size_t)tok[m0 + ar] * 768 + ch;
    const u16* ap1 = E + (size_t)tok[m0 + 64 + ar] * 768 + ch;
    const u16* bp0 = Wt + (size_t)(n0 + ar) * 768 + ch;
    const u16* bp1 = Wt + (size_t)(n0 + 64 + ar) * 768 + ch;
    const int lane = tid & 63, wave = tid >> 6;
    const int wm = (wave >> 1) * 64, wn = (wave & 1) * 64;
    const int qr = lane >> 4, lr = lane & 15;
    f32x4 acc[4][4] = {};
    for (int k0 = 0; k0 < 768; k0 += 32){
        __syncthreads();
        *(short8*)&Asm[ar*32 + ch]      = *(const short8*)(ap0 + k0);
        *(short8*)&Asm[(64+ar)*32 + ch] = *(const short8*)(ap1 + k0);
        *(short8*)&Bsm[ar*32 + ch]      = *(const short8*)(bp0 + k0);
        *(short8*)&Bsm[(64+ar)*32 + ch] = *(const short8*)(bp1 + k0);
        __syncthreads();
        short8 af[4], bfr[4];
        #pragma unroll
        for (int i = 0; i < 4; ++i){
            af[i]  = *(const short8*)&Asm[(wm + i*16 + lr)*32 + qr*8];
            bfr[i] = *(const short8*)&Bsm[(wn + i*16 + lr)*32 + qr*8];
        }
        #pragma unroll
        for (int i = 0; i < 4; ++i)
            #pragma unroll
            for (int j = 0; j < 4; ++j)
                acc[i][j] = __builtin_amdgcn_mfma_f32_16x16x32_bf16(af[i], bfr[j], acc[i][j], 0, 0, 0);
    }
    #pragma unroll
    for (int j = 0; j < 4; ++j){
        int col = n0 + wn + j*16 + lr;
        int d = col >> 9, p = col & 511;
        int uu = p >> 2, gg = p & 3;
        float bias = (d ? bb_ : bf_)[gg*128 + uu];
        #pragma unroll
        for (int i = 0; i < 4; ++i){
            #pragma unroll
            for (int r = 0; r < 4; ++r){
                int row = m0 + wm + i*16 + qr*4 + r;
                pre[(size_t)row*1024 + col] = f2b(acc[i][j][r] + bias);
            }
        }
    }
}

// ---------------- batched MFMA LSTM recurrence ----------------
// One block per (direction, group of 16 chains). 512 threads = 8 waves.
// Per step: C[512 gate-rows x 16 batches] = W_hh_perm[512x128] @ h[16x128]^T  (MFMA),
// acc initialized from precomputed pre (bias included).
// Lane layout (16x16x32 C): row=(lane>>4)*4+reg, col=lane&15 -> with permuted rows
// (p = unit*4+gate) each lane's f32x4 acc holds gates (i,f,g,o) of unit
// u = wave*16 + i*4 + qr for batch lr.  Cell state c stays in registers all T steps;
// h goes through XOR-swizzled double-buffered LDS (bf16).
// Step-loop barrier is lgkmcnt-only (raw s_barrier): global h-stores stay in flight
// across steps -- NO per-step vmcnt(0) drain (that drain was 2.7us/step in round 1).
__global__ __launch_bounds__(512, 2) void lstm_rec(
    const u16* __restrict__ preW, const u16* __restrict__ preS,
    const u16* __restrict__ Whp,     // [4][512][128] bf16: wordF, wordB, sentF, sentB
    float* __restrict__ fo, float* __restrict__ fs,
    u16* __restrict__ foB, u16* __restrict__ fsB)
{
    const int bg = blockIdx.x;
    const u16* pre; const u16* wh; float* out; u16* outB;
    int T, dir, grp;
    if (bg < 4){                      // word: 2 groups x 2 dirs, T=1024
        dir = bg & 1; grp = bg >> 1;
        T = 1024; pre = preW; wh = Whp + (size_t)dir*512*128;
        out = fo; outB = foB;
    } else {                          // sent: 32 groups x 2 dirs, T=64
        int s = bg - 4; dir = s & 1; grp = s >> 1;
        T = 64; pre = preS; wh = Whp + (size_t)(2+dir)*512*128;
        out = fs; outB = fsB;
    }
    const int tid  = threadIdx.x;
    const int wave = tid >> 6, lane = tid & 63;
    const int lr = lane & 15, qr = lane >> 4;

    const long rowBase = (long)(grp*16 + lr) * T;   // row stride == T for both cases
    const int t0 = dir ? (T-1) : 0;
    const int dt = dir ? -1 : 1;

    // A-fragments: W_hh rows for this wave, resident in VGPRs for all T steps
    short8 aw[4][4];
    #pragma unroll
    for (int i = 0; i < 4; ++i)
        #pragma unroll
        for (int kk = 0; kk < 4; ++kk)
            aw[i][kk] = *(const short8*)(wh + (size_t)(wave*64 + i*16 + lr)*128 + kk*32 + qr*8);

    // single base pointers; i-offsets are compile-time immediates
    const int u0 = wave*16 + qr;                       // i adds 4
    const u16* pp = pre  + (rowBase + t0)*1024 + dir*512 + u0*4;   // +i*16 (u16)
    float*    po = out  + (rowBase + t0)*256  + dir*128 + u0;      // +i*4  (f32)
    u16*      pb = outB + (rowBase + t0)*256  + dir*128 + u0;      // +i*4  (u16)
    const long pstep = (long)dt * 1024;
    const long ostep = (long)dt * 256;

    // double-buffered h, bf16, 4-bit XOR swizzle (16B granules) on write AND read
    __shared__ __align__(16) u16 hb[2][16*128];
    for (int k = tid; k < 16*128; k += 512) hb[0][k] = 0;
    const int rsw = lr << 3;                           // (lr&15)*8 u16 = granule XOR

    float cst[4] = {0.f, 0.f, 0.f, 0.f};
    ushort4 pc[4];
    #pragma unroll
    for (int i = 0; i < 4; ++i) pc[i] = *(const ushort4*)(pp + i*16);
    __syncthreads();

    int cur = 0;
    for (int t = 0; t < T; ++t){
        // prefetch next step's pre (last iter reads in-workspace garbage, unused)
        ushort4 pn[4];
        pp += pstep;
        #pragma unroll
        for (int i = 0; i < 4; ++i) pn[i] = *(const ushort4*)(pp + i*16);

        // B-fragments: h rows (batch = lr), swizzled
        short8 bfr[4];
        #pragma unroll
        for (int kk = 0; kk < 4; ++kk)
            bfr[kk] = *(const short8*)&hb[cur][lr*128 + ((kk*32 + qr*8) ^ rsw)];

        #pragma unroll
        for (int i = 0; i < 4; ++i){
            f32x4 acc;
            acc[0] = b2f(pc[i].x); acc[1] = b2f(pc[i].y);
            acc[2] = b2f(pc[i].z); acc[3] = b2f(pc[i].w);
            #pragma unroll
            for (int kk = 0; kk < 4; ++kk)
                acc = __builtin_amdgcn_mfma_f32_16x16x32_bf16(aw[i][kk], bfr[kk], acc, 0, 0, 0);
            float gi = sigm(acc[0]), gf = sigm(acc[1]);
            float gg = tanhf2(acc[2]), go = sigm(acc[3]);
            float c = gf*cst[i] + gi*gg;
            cst[i] = c;
            float h = go * tanhf2(c);
            po[i*4] = h;                         // fire-and-forget, never drained in-loop
            u16 hv = f2b(h);
            pb[i*4] = hv;
            hb[cur^1][lr*128 + ((u0 + i*4) ^ rsw)] = hv;
        }
        po += ostep; pb += ostep;
        // LDS-only barrier: order the h exchange, leave global stores in flight
        asm volatile("s_waitcnt lgkmcnt(0)" ::: "memory");
        __builtin_amdgcn_s_barrier();
        cur ^= 1;
        #pragma unroll
        for (int i = 0; i < 4; ++i) pc[i] = pn[i];
    }
}

// ---------------- gate GEMM + blend epilogue ----------------
// gamma = sigmoid([fo|fs] @ gW^T + gb); out = gamma*fo + (1-gamma)*fs
__global__ __launch_bounds__(256) void gemm_gate(
    const u16* __restrict__ foB, const u16* __restrict__ fsB,
    const u16* __restrict__ gW, const float* __restrict__ gb,
    const float* __restrict__ fo, const float* __restrict__ fs,
    float* __restrict__ out)
{
    __shared__ __align__(16) u16 Asm[128*32];
    __shared__ __align__(16) u16 Bsm[128*32];
    const int m0 = blockIdx.x * 128, n0 = blockIdx.y * 128;
    const int tid = threadIdx.x;
    const int ar = tid >> 2, ch = (tid & 3) * 8;
    const u16* af0 = foB + (size_t)(m0 + ar) * 256 + ch;
    const u16* af1 = foB + (size_t)(m0 + 64 + ar) * 256 + ch;
    const u16* as0 = fsB + (size_t)(m0 + ar) * 256 + ch;
    const u16* as1 = fsB + (size_t)(m0 + 64 + ar) * 256 + ch;
    const u16* bp0 = gW + (size_t)(n0 + ar) * 512 + ch;
    const u16* bp1 = gW + (size_t)(n0 + 64 + ar) * 512 + ch;
    const int lane = tid & 63, wave = tid >> 6;
    const int wm = (wave >> 1) * 64, wn = (wave & 1) * 64;
    const int qr = lane >> 4, lr = lane & 15;
    f32x4 acc[4][4] = {};
    for (int k0 = 0; k0 < 512; k0 += 32){
        __syncthreads();
        const u16* s0 = (k0 < 256) ? (af0 + k0) : (as0 + (k0 - 256));
        const u16* s1 = (k0 < 256) ? (af1 + k0) : (as1 + (k0 - 256));
        *(short8*)&Asm[ar*32 + ch]      = *(const short8*)s0;
        *(short8*)&Asm[(64+ar)*32 + ch] = *(const short8*)s1;
        *(short8*)&Bsm[ar*32 + ch]      = *(const short8*)(bp0 + k0);
        *(short8*)&Bsm[(64+ar)*32 + ch] = *(const short8*)(bp1 + k0);
        __syncthreads();
        short8 af[4], bfr[4];
        #pragma unroll
        for (int i = 0; i < 4; ++i){
            af[i]  = *(const short8*)&Asm[(wm + i*16 + lr)*32 + qr*8];
            bfr[i] = *(const short8*)&Bsm[(wn + i*16 + lr)*32 + qr*8];
        }
        #pragma unroll
        for (int i = 0; i < 4; ++i)
            #pragma unroll
            for (int j = 0; j < 4; ++j)
                acc[i][j] = __builtin_amdgcn_mfma_f32_16x16x32_bf16(af[i], bfr[j], acc[i][j], 0, 0, 0);
    }
    #pragma unroll
    for (int j = 0; j < 4; ++j){
        int col = n0 + wn + j*16 + lr;   // 0..255
        float bias = gb[col];
        #pragma unroll
        for (int i = 0; i < 4; ++i){
            #pragma unroll
            for (int r = 0; r < 4; ++r){
                int row = m0 + wm + i*16 + qr*4 + r;
                size_t o = (size_t)row*256 + col;
                float gamma = sigm(acc[i][j][r] + bias);
                out[o] = gamma * fo[o] + (1.f - gamma) * fs[o];
            }
        }
    }
}

extern "C" void kernel_launch(void* const* d_in, const int* in_sizes, int n_in,
                              void* d_out, int out_size, void* d_ws, size_t ws_size,
                              hipStream_t stream)
{
    (void)in_sizes; (void)n_in; (void)out_size; (void)ws_size;
    const int*   wordTok = (const int*)d_in[0];
    const int*   sentTok = (const int*)d_in[1];
    const float* E       = (const float*)d_in[3];
    const float* WihWf   = (const float*)d_in[4];
    const float* WhhWf   = (const float*)d_in[5];
    const float* bWf     = (const float*)d_in[6];
    const float* WihWb   = (const float*)d_in[7];
    const float* WhhWb   = (const float*)d_in[8];
    const float* bWb     = (const float*)d_in[9];
    const float* WihSf   = (const float*)d_in[10];
    const float* WhhSf   = (const float*)d_in[11];
    const float* bSf     = (const float*)d_in[12];
    const float* WihSb   = (const float*)d_in[13];
    const float* WhhSb   = (const float*)d_in[14];
    const float* bSb     = (const float*)d_in[15];
    const float* gateW   = (const float*)d_in[16];
    const float* gateB   = (const float*)d_in[17];
    float* out = (float*)d_out;

    char* w = (char*)d_ws;
    u16* Eb   = (u16*)w;  w += (size_t)30522*768*2;
    u16* Ww   = (u16*)w;  w += (size_t)1024*768*2;
    u16* Ws_  = (u16*)w;  w += (size_t)1024*768*2;
    u16* gWb  = (u16*)w;  w += (size_t)256*512*2;
    u16* preW = (u16*)w;  w += (size_t)32768*1024*2;
    u16* preS = (u16*)w;  w += (size_t)32768*1024*2;
    float* fo = (float*)w; w += (size_t)32768*256*4;
    float* fs = (float*)w; w += (size_t)32768*256*4;
    u16* foB  = (u16*)w;  w += (size_t)32768*256*2;
    u16* fsB  = (u16*)w;  w += (size_t)32768*256*2;
    u16* Whp  = (u16*)w;  w += (size_t)4*512*128*2;

    const int nE4 = 30522*768/4;
    cvt_bf16<<<(nE4+255)/256, 256, 0, stream>>>(E, Eb, nE4);
    cvt_wih_perm<<<512, 192, 0, stream>>>(WihWf, Ww);
    cvt_wih_perm<<<512, 192, 0, stream>>>(WihWb, Ww + 512*768);
    cvt_wih_perm<<<512, 192, 0, stream>>>(WihSf, Ws_);
    cvt_wih_perm<<<512, 192, 0, stream>>>(WihSb, Ws_ + 512*768);
    const int nG4 = 256*512/4;
    cvt_bf16<<<(nG4+255)/256, 256, 0, stream>>>(gateW, gWb, nG4);
    cvt_whh_perm<<<64, 256, 0, stream>>>(WhhWf, Whp);
    cvt_whh_perm<<<64, 256, 0, stream>>>(WhhWb, Whp + 512*128);
    cvt_whh_perm<<<64, 256, 0, stream>>>(WhhSf, Whp + 2*512*128);
    cvt_whh_perm<<<64, 256, 0, stream>>>(WhhSb, Whp + 3*512*128);

    gemm_embed<<<dim3(256,8), 256, 0, stream>>>(Eb, wordTok, Ww, bWf, bWb, preW);
    gemm_embed<<<dim3(256,8), 256, 0, stream>>>(Eb, sentTok, Ws_, bSf, bSb, preS);
    lstm_rec<<<68, 512, 0, stream>>>(preW, preS, Whp, fo, fs, foB, fsB);
    gemm_gate<<<dim3(256,2), 256, 0, stream>>>(foB, fsB, gWb, gateB, fo, fs, out);
}

// Round 3
// 2148.118 us; speedup vs baseline: 1.5884x; 1.5884x over previous
//
#include <hip/hip_runtime.h>

typedef unsigned short u16;
typedef __attribute__((ext_vector_type(8))) short short8;
typedef __attribute__((ext_vector_type(4))) float f32x4;

__device__ __forceinline__ u16 f2b(float f){
    unsigned u = __builtin_bit_cast(unsigned, f);
    u += 0x7fffu + ((u >> 16) & 1u);   // RNE
    return (u16)(u >> 16);
}
__device__ __forceinline__ float b2f(u16 s){
    unsigned u = ((unsigned)s) << 16;
    return __builtin_bit_cast(float, u);
}
__device__ __forceinline__ float sigm(float x){ return 1.f/(1.f + __expf(-x)); }
// branch-free tanh: 1 - 2/(1+e^{2x})
__device__ __forceinline__ float tanhf2(float x){
    float e = __expf(2.f * x);
    return 1.f - 2.f/(1.f + e);
}

// ---------------- fp32 -> bf16 conversion ----------------
__global__ __launch_bounds__(256) void cvt_bf16(const float* __restrict__ s,
                                                u16* __restrict__ d, int n4){
    int i = blockIdx.x*256 + threadIdx.x;
    if (i < n4){
        float4 v = ((const float4*)s)[i];
        ushort4 o;
        o.x = f2b(v.x); o.y = f2b(v.y); o.z = f2b(v.z); o.w = f2b(v.w);
        ((ushort4*)d)[i] = o;
    }
}

// ---- W_ih cvt with row permutation: out row (unit*4+gate) = in row (gate*128+unit) ----
__global__ __launch_bounds__(192) void cvt_wih_perm(const float* __restrict__ s,
                                                    u16* __restrict__ d){
    int r = blockIdx.x;               // 0..511 input row
    int j = threadIdx.x;              // 0..191 float4 within row
    int g = r >> 7, u = r & 127;
    int ro = u * 4 + g;
    float4 v = ((const float4*)(s + (size_t)r * 768))[j];
    ushort4 o;
    o.x = f2b(v.x); o.y = f2b(v.y); o.z = f2b(v.z); o.w = f2b(v.w);
    ((ushort4*)(d + (size_t)ro * 768))[j] = o;
}

// ---- W_hh cvt with the same row permutation, 128 cols, bf16 out ----
__global__ __launch_bounds__(256) void cvt_whh_perm(const float* __restrict__ s,
                                                    u16* __restrict__ d){
    int idx = blockIdx.x*256 + threadIdx.x;   // 0..16383
    if (idx >= 512*32) return;
    int r = idx >> 5, j = idx & 31;           // row, float4 within row
    int g = r >> 7, u = r & 127;
    int ro = u * 4 + g;
    float4 v = ((const float4*)(s + (size_t)r * 128))[j];
    ushort4 o;
    o.x = f2b(v.x); o.y = f2b(v.y); o.z = f2b(v.z); o.w = f2b(v.w);
    ((ushort4*)(d + (size_t)ro * 128))[j] = o;
}

// ---------------- embedding-gather + input projection GEMM ----------------
// pre-activations are written in the LANE-EXACT layout lstm_rec consumes:
//   idx = ((blk*Tdim + t) * 512 + tidL) * 16 + iL*4 + g   (u16 units)
// where for the lstm lane (waveL,qrL,lrL): tidL = waveL*64+qrL*16+lrL,
// gate-row p = u*4+g, u = waveL*16 + iL*4 + qrL, chain low bits lrL.
// word: blk = dir*2 + (chain>>4), Tdim=1024;  sent: blk = dir*32 + (chain>>4), Tdim=64.
__global__ __launch_bounds__(256) void gemm_embed(
    const u16* __restrict__ E, const int* __restrict__ tok,
    const u16* __restrict__ Wt, const float* __restrict__ bf_,
    const float* __restrict__ bb_, u16* __restrict__ pre, int sentMode)
{
    __shared__ __align__(16) u16 Asm[128*32];
    __shared__ __align__(16) u16 Bsm[128*32];
    const int m0 = blockIdx.x * 128, n0 = blockIdx.y * 128;
    const int tid = threadIdx.x;
    const int ar = tid >> 2, ch = (tid & 3) * 8;
    const u16* ap0 = E + (size_t)tok[m0 + ar] * 768 + ch;
    const u16* ap1 = E + (size_t)tok[m0 + 64 + ar] * 768 + ch;
    const u16* bp0 = Wt + (size_t)(n0 + ar) * 768 + ch;
    const u16* bp1 = Wt + (size_t)(n0 + 64 + ar) * 768 + ch;
    const int lane = tid & 63, wave = tid >> 6;
    const int wm = (wave >> 1) * 64, wn = (wave & 1) * 64;
    const int qr = lane >> 4, lr = lane & 15;
    f32x4 acc[4][4] = {};
    for (int k0 = 0; k0 < 768; k0 += 32){
        __syncthreads();
        *(short8*)&Asm[ar*32 + ch]      = *(const short8*)(ap0 + k0);
        *(short8*)&Asm[(64+ar)*32 + ch] = *(const short8*)(ap1 + k0);
        *(short8*)&Bsm[ar*32 + ch]      = *(const short8*)(bp0 + k0);
        *(short8*)&Bsm[(64+ar)*32 + ch] = *(const short8*)(bp1 + k0);
        __syncthreads();
        short8 af[4], bfr[4];
        #pragma unroll
        for (int i = 0; i < 4; ++i){
            af[i]  = *(const short8*)&Asm[(wm + i*16 + lr)*32 + qr*8];
            bfr[i] = *(const short8*)&Bsm[(wn + i*16 + lr)*32 + qr*8];
        }
        #pragma unroll
        for (int i = 0; i < 4; ++i)
            #pragma unroll
            for (int j = 0; j < 4; ++j)
                acc[i][j] = __builtin_amdgcn_mfma_f32_16x16x32_bf16(af[i], bfr[j], acc[i][j], 0, 0, 0);
    }
    #pragma unroll
    for (int j = 0; j < 4; ++j){
        int col = n0 + wn + j*16 + lr;
        int dirO = col >> 9, pcol = col & 511;
        int uu = pcol >> 2, gg = pcol & 3;
        float bias = (dirO ? bb_ : bf_)[gg*128 + uu];
        int tidBase = ((uu >> 4) << 6) | ((uu & 3) << 4);   // waveL*64 + qrL*16
        int ig4 = (((uu >> 2) & 3) << 2) | gg;              // iL*4 + g
        #pragma unroll
        for (int i = 0; i < 4; ++i){
            #pragma unroll
            for (int r = 0; r < 4; ++r){
                int mrow = m0 + wm + i*16 + qr*4 + r;
                int chain, t, blk, Tdim;
                if (sentMode){ chain = mrow >> 6;  t = mrow & 63;   blk = dirO*32 + (chain >> 4); Tdim = 64; }
                else         { chain = mrow >> 10; t = mrow & 1023; blk = dirO*2  + (chain >> 4); Tdim = 1024; }
                size_t idx = (((size_t)blk * Tdim + t) * 512 + (tidBase + (chain & 15))) * 16 + ig4;
                pre[idx] = f2b(acc[i][j][r] + bias);
            }
        }
    }
}

// ---------------- batched MFMA LSTM recurrence ----------------
// One block per (direction, group of 16 chains). 512 threads = 8 waves.
// Per step: C[512 gate-rows x 16 chains] = W_hh_perm[512x128] @ h[16x128]^T (MFMA),
// acc initialized from lane-exact precomputed pre (bias included).
// Per lane: gates (i,f,g,o) of unit u = wave*16 + i*4 + qr for chain lr.
// Cell state c in registers all T steps. h exchanged via XOR-swizzled bf16 LDS dbuf.
// OUTPUT: f32 h accumulates in a 64KB swizzled LDS history; flushed every 8 steps
// with fully-coalesced float4 stores (r2's scattered per-step stores were ~1100
// mem-transactions/CU/step on only 4 CUs -> the 7000cyc/step stall).
__global__ __launch_bounds__(512, 2) void lstm_rec(
    const u16* __restrict__ preW, const u16* __restrict__ preS,
    const u16* __restrict__ Whp,     // [4][512][128] bf16: wordF, wordB, sentF, sentB
    float* __restrict__ fo, float* __restrict__ fs)
{
    const int bg = blockIdx.x;
    const u16* preBlk; const u16* wh; float* out;
    int T, dir, grp;
    if (bg < 4){                      // word: 2 groups x 2 dirs, T=1024
        dir = bg & 1; grp = bg >> 1; T = 1024;
        preBlk = preW + (size_t)(dir*2 + grp) * 1024 * 8192;
        wh = Whp + (size_t)dir*512*128; out = fo;
    } else {                          // sent: 32 groups x 2 dirs, T=64
        int s = bg - 4; dir = s & 1; grp = s >> 1; T = 64;
        preBlk = preS + (size_t)(dir*32 + grp) * 64 * 8192;
        wh = Whp + (size_t)(2+dir)*512*128; out = fs;
    }
    const int tid  = threadIdx.x;
    const int wave = tid >> 6, lane = tid & 63;
    const int lr = lane & 15, qr = lane >> 4;
    const int u0 = wave*16 + qr;
    const int t0 = dir ? (T-1) : 0;
    const int dt = dir ? -1 : 1;

    // A-fragments: W_hh rows resident for all T steps
    short8 aw[4][4];
    #pragma unroll
    for (int i = 0; i < 4; ++i)
        #pragma unroll
        for (int kk = 0; kk < 4; ++kk)
            aw[i][kk] = *(const short8*)(wh + (size_t)(wave*64 + i*16 + lr)*128 + kk*32 + qr*8);

    __shared__ __align__(16) u16   hb[2][16*128];     // bf16 h exchange (8KB)
    __shared__ __align__(16) float hist[8*16*128];    // f32 h history (64KB)
    for (int k = tid; k < 16*128; k += 512) hb[0][k] = 0;
    const int rsw = lr << 3;          // 8-u16 (16B) granule XOR for hb
    const int fsw = lr << 2;          // 4-f32 (16B) granule XOR for hist

    // pre loads: 32B/lane/step, contiguous per wave (2KB/wave). prefetch depth 2.
    const long pstep = (long)dt * 8192;
    const u16* p = preBlk + (size_t)t0 * 8192 + tid*16;
    short8 c0 = *(const short8*)p,        c1 = *(const short8*)(p + 8);
    short8 d0 = *(const short8*)(p+pstep), d1 = *(const short8*)(p+pstep+8);
    p += 2*pstep;

    float cst[4] = {0.f, 0.f, 0.f, 0.f};
    __syncthreads();

    for (int it = 0; it < T; ++it){
        // prefetch it+2 (tail reads adjacent workspace garbage, unused)
        short8 e0 = *(const short8*)p, e1 = *(const short8*)(p + 8);
        p += pstep;

        const int cur = it & 1;
        short8 bfr[4];
        #pragma unroll
        for (int kk = 0; kk < 4; ++kk)
            bfr[kk] = *(const short8*)&hb[cur][lr*128 + ((kk*32 + qr*8) ^ rsw)];

        u16*   hw = &hb[cur ^ 1][lr*128];
        float* hh = &hist[(it & 7)*2048 + lr*128];
        #pragma unroll
        for (int i = 0; i < 4; ++i){
            short8 cs = (i < 2) ? c0 : c1;
            const int o = (i & 1) * 4;
            f32x4 acc;
            acc[0] = b2f((u16)cs[o+0]); acc[1] = b2f((u16)cs[o+1]);
            acc[2] = b2f((u16)cs[o+2]); acc[3] = b2f((u16)cs[o+3]);
            #pragma unroll
            for (int kk = 0; kk < 4; ++kk)
                acc = __builtin_amdgcn_mfma_f32_16x16x32_bf16(aw[i][kk], bfr[kk], acc, 0, 0, 0);
            float gi = sigm(acc[0]), gf = sigm(acc[1]);
            float gg = tanhf2(acc[2]), go = sigm(acc[3]);
            float c = gf*cst[i] + gi*gg;
            cst[i] = c;
            float h = go * tanhf2(c);
            int u = u0 + i*4;
            hw[u ^ rsw] = f2b(h);
            hh[u ^ fsw] = h;
        }
        asm volatile("s_waitcnt lgkmcnt(0)" ::: "memory");
        __builtin_amdgcn_s_barrier();
        c0 = d0; c1 = d1; d0 = e0; d1 = e1;

        if ((it & 7) == 7){
            // coalesced flush of 8 completed steps (64KB f32)
            const int itB = it - 7;
            #pragma unroll
            for (int j = 0; j < 8; ++j){
                int lin  = j*512 + tid;
                int u4   = (lin & 31) * 4;          // f32 col (x4)
                int pair = lin >> 5;
                int s = pair & 7, ch = pair >> 3;
                float4 v = *(const float4*)&hist[s*2048 + ch*128 + (u4 ^ (ch << 2))];
                int tt = t0 + dt*(itB + s);
                *(float4*)(out + ((size_t)(grp*16 + ch)*T + tt)*256 + dir*128 + u4) = v;
            }
            asm volatile("s_waitcnt lgkmcnt(0)" ::: "memory");
            __builtin_amdgcn_s_barrier();       // hist safe to overwrite next step
        }
    }
}

// ---------------- gate GEMM + blend epilogue ----------------
// gamma = sigmoid([fo|fs] @ gW^T + gb); out = gamma*fo + (1-gamma)*fs
// A-operand staged from f32 fo/fs with on-the-fly bf16 conversion (foB/fsB removed).
__global__ __launch_bounds__(256) void gemm_gate(
    const u16* __restrict__ gW, const float* __restrict__ gb,
    const float* __restrict__ fo, const float* __restrict__ fs,
    float* __restrict__ out)
{
    __shared__ __align__(16) u16 Asm[128*32];
    __shared__ __align__(16) u16 Bsm[128*32];
    const int m0 = blockIdx.x * 128, n0 = blockIdx.y * 128;
    const int tid = threadIdx.x;
    const int ar = tid >> 2, ch = (tid & 3) * 8;
    const float* af0 = fo + (size_t)(m0 + ar) * 256 + ch;
    const float* af1 = fo + (size_t)(m0 + 64 + ar) * 256 + ch;
    const float* as0 = fs + (size_t)(m0 + ar) * 256 + ch;
    const float* as1 = fs + (size_t)(m0 + 64 + ar) * 256 + ch;
    const u16* bp0 = gW + (size_t)(n0 + ar) * 512 + ch;
    const u16* bp1 = gW + (size_t)(n0 + 64 + ar) * 512 + ch;
    const int lane = tid & 63, wave = tid >> 6;
    const int wm = (wave >> 1) * 64, wn = (wave & 1) * 64;
    const int qr = lane >> 4, lr = lane & 15;
    f32x4 acc[4][4] = {};
    for (int k0 = 0; k0 < 512; k0 += 32){
        __syncthreads();
        const float* s0 = (k0 < 256) ? (af0 + k0) : (as0 + (k0 - 256));
        const float* s1 = (k0 < 256) ? (af1 + k0) : (as1 + (k0 - 256));
        float4 x0 = ((const float4*)s0)[0], x1 = ((const float4*)s0)[1];
        float4 y0 = ((const float4*)s1)[0], y1 = ((const float4*)s1)[1];
        ushort4 a0; a0.x=f2b(x0.x); a0.y=f2b(x0.y); a0.z=f2b(x0.z); a0.w=f2b(x0.w);
        ushort4 a1; a1.x=f2b(x1.x); a1.y=f2b(x1.y); a1.z=f2b(x1.z); a1.w=f2b(x1.w);
        ushort4 b0; b0.x=f2b(y0.x); b0.y=f2b(y0.y); b0.z=f2b(y0.z); b0.w=f2b(y0.w);
        ushort4 b1; b1.x=f2b(y1.x); b1.y=f2b(y1.y); b1.z=f2b(y1.z); b1.w=f2b(y1.w);
        *(ushort4*)&Asm[ar*32 + ch]          = a0;
        *(ushort4*)&Asm[ar*32 + ch + 4]      = a1;
        *(ushort4*)&Asm[(64+ar)*32 + ch]     = b0;
        *(ushort4*)&Asm[(64+ar)*32 + ch + 4] = b1;
        *(short8*)&Bsm[ar*32 + ch]      = *(const short8*)(bp0 + k0);
        *(short8*)&Bsm[(64+ar)*32 + ch] = *(const short8*)(bp1 + k0);
        __syncthreads();
        short8 af[4], bfr[4];
        #pragma unroll
        for (int i = 0; i < 4; ++i){
            af[i]  = *(const short8*)&Asm[(wm + i*16 + lr)*32 + qr*8];
            bfr[i] = *(const short8*)&Bsm[(wn + i*16 + lr)*32 + qr*8];
        }
        #pragma unroll
        for (int i = 0; i < 4; ++i)
            #pragma unroll
            for (int j = 0; j < 4; ++j)
                acc[i][j] = __builtin_amdgcn_mfma_f32_16x16x32_bf16(af[i], bfr[j], acc[i][j], 0, 0, 0);
    }
    #pragma unroll
    for (int j = 0; j < 4; ++j){
        int col = n0 + wn + j*16 + lr;   // 0..255
        float bias = gb[col];
        #pragma unroll
        for (int i = 0; i < 4; ++i){
            #pragma unroll
            for (int r = 0; r < 4; ++r){
                int row = m0 + wm + i*16 + qr*4 + r;
                size_t o = (size_t)row*256 + col;
                float gamma = sigm(acc[i][j][r] + bias);
                out[o] = gamma * fo[o] + (1.f - gamma) * fs[o];
            }
        }
    }
}

extern "C" void kernel_launch(void* const* d_in, const int* in_sizes, int n_in,
                              void* d_out, int out_size, void* d_ws, size_t ws_size,
                              hipStream_t stream)
{
    (void)in_sizes; (void)n_in; (void)out_size; (void)ws_size;
    const int*   wordTok = (const int*)d_in[0];
    const int*   sentTok = (const int*)d_in[1];
    const float* E       = (const float*)d_in[3];
    const float* WihWf   = (const float*)d_in[4];
    const float* WhhWf   = (const float*)d_in[5];
    const float* bWf     = (const float*)d_in[6];
    const float* WihWb   = (const float*)d_in[7];
    const float* WhhWb   = (const float*)d_in[8];
    const float* bWb     = (const float*)d_in[9];
    const float* WihSf   = (const float*)d_in[10];
    const float* WhhSf   = (const float*)d_in[11];
    const float* bSf     = (const float*)d_in[12];
    const float* WihSb   = (const float*)d_in[13];
    const float* WhhSb   = (const float*)d_in[14];
    const float* bSb     = (const float*)d_in[15];
    const float* gateW   = (const float*)d_in[16];
    const float* gateB   = (const float*)d_in[17];
    float* out = (float*)d_out;

    char* w = (char*)d_ws;
    u16* Eb   = (u16*)w;  w += (size_t)30522*768*2;
    u16* Ww   = (u16*)w;  w += (size_t)1024*768*2;
    u16* Ws_  = (u16*)w;  w += (size_t)1024*768*2;
    u16* gWb  = (u16*)w;  w += (size_t)256*512*2;
    u16* preW = (u16*)w;  w += (size_t)32768*1024*2;
    u16* preS = (u16*)w;  w += (size_t)32768*1024*2;
    float* fo = (float*)w; w += (size_t)32768*256*4;
    float* fs = (float*)w; w += (size_t)32768*256*4;
    u16* Whp  = (u16*)w;  w += (size_t)4*512*128*2;

    const int nE4 = 30522*768/4;
    cvt_bf16<<<(nE4+255)/256, 256, 0, stream>>>(E, Eb, nE4);
    cvt_wih_perm<<<512, 192, 0, stream>>>(WihWf, Ww);
    cvt_wih_perm<<<512, 192, 0, stream>>>(WihWb, Ww + 512*768);
    cvt_wih_perm<<<512, 192, 0, stream>>>(WihSf, Ws_);
    cvt_wih_perm<<<512, 192, 0, stream>>>(WihSb, Ws_ + 512*768);
    const int nG4 = 256*512/4;
    cvt_bf16<<<(nG4+255)/256, 256, 0, stream>>>(gateW, gWb, nG4);
    cvt_whh_perm<<<64, 256, 0, stream>>>(WhhWf, Whp);
    cvt_whh_perm<<<64, 256, 0, stream>>>(WhhWb, Whp + 512*128);
    cvt_whh_perm<<<64, 256, 0, stream>>>(WhhSf, Whp + 2*512*128);
    cvt_whh_perm<<<64, 256, 0, stream>>>(WhhSb, Whp + 3*512*128);

    gemm_embed<<<dim3(256,8), 256, 0, stream>>>(Eb, wordTok, Ww, bWf, bWb, preW, 0);
    gemm_embed<<<dim3(256,8), 256, 0, stream>>>(Eb, sentTok, Ws_, bSf, bSb, preS, 1);
    lstm_rec<<<68, 512, 0, stream>>>(preW, preS, Whp, fo, fs);
    gemm_gate<<<dim3(256,2), 256, 0, stream>>>(gWb, gateB, fo, fs, out);
}

// Round 4
// 2019.320 us; speedup vs baseline: 1.6897x; 1.0638x over previous
//
#include <hip/hip_runtime.h>

typedef unsigned short u16;
typedef __attribute__((ext_vector_type(8))) short short8;
typedef __attribute__((ext_vector_type(4))) float f32x4;

__device__ __forceinline__ u16 f2b(float f){
    unsigned u = __builtin_bit_cast(unsigned, f);
    u += 0x7fffu + ((u >> 16) & 1u);   // RNE
    return (u16)(u >> 16);
}
__device__ __forceinline__ float b2f(u16 s){
    unsigned u = ((unsigned)s) << 16;
    return __builtin_bit_cast(float, u);
}
__device__ __forceinline__ float sigm(float x){ return 1.f/(1.f + __expf(-x)); }
// branch-free tanh: 1 - 2/(1+e^{2x})
__device__ __forceinline__ float tanhf2(float x){
    float e = __expf(2.f * x);
    return 1.f - 2.f/(1.f + e);
}

// ---------------- fp32 -> bf16 conversion ----------------
__global__ __launch_bounds__(256) void cvt_bf16(const float* __restrict__ s,
                                                u16* __restrict__ d, int n4){
    int i = blockIdx.x*256 + threadIdx.x;
    if (i < n4){
        float4 v = ((const float4*)s)[i];
        ushort4 o;
        o.x = f2b(v.x); o.y = f2b(v.y); o.z = f2b(v.z); o.w = f2b(v.w);
        ((ushort4*)d)[i] = o;
    }
}

// ---- W_ih cvt with row permutation: out row (unit*4+gate) = in row (gate*128+unit) ----
__global__ __launch_bounds__(192) void cvt_wih_perm(const float* __restrict__ s,
                                                    u16* __restrict__ d){
    int r = blockIdx.x;               // 0..511 input row
    int j = threadIdx.x;              // 0..191 float4 within row
    int g = r >> 7, u = r & 127;
    int ro = u * 4 + g;
    float4 v = ((const float4*)(s + (size_t)r * 768))[j];
    ushort4 o;
    o.x = f2b(v.x); o.y = f2b(v.y); o.z = f2b(v.z); o.w = f2b(v.w);
    ((ushort4*)(d + (size_t)ro * 768))[j] = o;
}

// ---- W_hh cvt with the same row permutation, 128 cols, bf16 out ----
__global__ __launch_bounds__(256) void cvt_whh_perm(const float* __restrict__ s,
                                                    u16* __restrict__ d){
    int idx = blockIdx.x*256 + threadIdx.x;   // 0..16383
    if (idx >= 512*32) return;
    int r = idx >> 5, j = idx & 31;           // row, float4 within row
    int g = r >> 7, u = r & 127;
    int ro = u * 4 + g;
    float4 v = ((const float4*)(s + (size_t)r * 128))[j];
    ushort4 o;
    o.x = f2b(v.x); o.y = f2b(v.y); o.z = f2b(v.z); o.w = f2b(v.w);
    ((ushort4*)(d + (size_t)ro * 128))[j] = o;
}

// ---------------- embedding-gather + input projection GEMM ----------------
// pre-activations are written in the LANE-EXACT layout lstm_rec consumes:
//   idx = ((blk*Tdim + t) * 512 + tidL) * 16 + iL*4 + g   (u16 units)
__global__ __launch_bounds__(256) void gemm_embed(
    const u16* __restrict__ E, const int* __restrict__ tok,
    const u16* __restrict__ Wt, const float* __restrict__ bf_,
    const float* __restrict__ bb_, u16* __restrict__ pre, int sentMode)
{
    __shared__ __align__(16) u16 Asm[128*32];
    __shared__ __align__(16) u16 Bsm[128*32];
    const int m0 = blockIdx.x * 128, n0 = blockIdx.y * 128;
    const int tid = threadIdx.x;
    const int ar = tid >> 2, ch = (tid & 3) * 8;
    const u16* ap0 = E + (size_t)tok[m0 + ar] * 768 + ch;
    const u16* ap1 = E + (size_t)tok[m0 + 64 + ar] * 768 + ch;
    const u16* bp0 = Wt + (size_t)(n0 + ar) * 768 + ch;
    const u16* bp1 = Wt + (size_t)(n0 + 64 + ar) * 768 + ch;
    const int lane = tid & 63, wave = tid >> 6;
    const int wm = (wave >> 1) * 64, wn = (wave & 1) * 64;
    const int qr = lane >> 4, lr = lane & 15;
    f32x4 acc[4][4] = {};
    for (int k0 = 0; k0 < 768; k0 += 32){
        __syncthreads();
        *(short8*)&Asm[ar*32 + ch]      = *(const short8*)(ap0 + k0);
        *(short8*)&Asm[(64+ar)*32 + ch] = *(const short8*)(ap1 + k0);
        *(short8*)&Bsm[ar*32 + ch]      = *(const short8*)(bp0 + k0);
        *(short8*)&Bsm[(64+ar)*32 + ch] = *(const short8*)(bp1 + k0);
        __syncthreads();
        short8 af[4], bfr[4];
        #pragma unroll
        for (int i = 0; i < 4; ++i){
            af[i]  = *(const short8*)&Asm[(wm + i*16 + lr)*32 + qr*8];
            bfr[i] = *(const short8*)&Bsm[(wn + i*16 + lr)*32 + qr*8];
        }
        #pragma unroll
        for (int i = 0; i < 4; ++i)
            #pragma unroll
            for (int j = 0; j < 4; ++j)
                acc[i][j] = __builtin_amdgcn_mfma_f32_16x16x32_bf16(af[i], bfr[j], acc[i][j], 0, 0, 0);
    }
    #pragma unroll
    for (int j = 0; j < 4; ++j){
        int col = n0 + wn + j*16 + lr;
        int dirO = col >> 9, pcol = col & 511;
        int uu = pcol >> 2, gg = pcol & 3;
        float bias = (dirO ? bb_ : bf_)[gg*128 + uu];
        int tidBase = ((uu >> 4) << 6) | ((uu & 3) << 4);   // waveL*64 + qrL*16
        int ig4 = (((uu >> 2) & 3) << 2) | gg;              // iL*4 + g
        #pragma unroll
        for (int i = 0; i < 4; ++i){
            #pragma unroll
            for (int r = 0; r < 4; ++r){
                int mrow = m0 + wm + i*16 + qr*4 + r;
                int chain, t, blk, Tdim;
                if (sentMode){ chain = mrow >> 6;  t = mrow & 63;   blk = dirO*32 + (chain >> 4); Tdim = 64; }
                else         { chain = mrow >> 10; t = mrow & 1023; blk = dirO*2  + (chain >> 4); Tdim = 1024; }
                size_t idx = (((size_t)blk * Tdim + t) * 512 + (tidBase + (chain & 15))) * 16 + ig4;
                pre[idx] = f2b(acc[i][j][r] + bias);
            }
        }
    }
}

// ---------------- batched MFMA LSTM recurrence ----------------
// One block per (direction, group of 16 chains). 512 threads = 8 waves.
// KEY FIX vs r3: __launch_bounds__(512) (no min-waves) -> VGPR cap 256, not 128.
// r3's (512,2) capped VGPR at 128 < ~165 live demand, so the compiler
// REMATERIALIZED the aw[] W_hh loads from global inside the step loop:
// 16 L2 round-trips feeding MFMAs every step = the ~3900cyc/step floor.
// Also: 4x-unrolled step loop with a statically-indexed 4-slot pre prefetch
// buffer (no register rotation -> vmcnt wait has 3 steps of slack), and a
// single barrier per step (16-slot hist: flush half while writing the other
// half -> no post-flush barrier needed).
__global__ __launch_bounds__(512) void lstm_rec(
    const u16* __restrict__ preW, const u16* __restrict__ preS,
    const u16* __restrict__ Whp,     // [4][512][128] bf16: wordF, wordB, sentF, sentB
    float* __restrict__ fo, float* __restrict__ fs)
{
    const int bg = blockIdx.x;
    const u16* preBlk; const u16* wh; float* out;
    int T, dir, grp;
    if (bg < 4){                      // word: 2 groups x 2 dirs, T=1024
        dir = bg & 1; grp = bg >> 1; T = 1024;
        preBlk = preW + (size_t)(dir*2 + grp) * 1024 * 8192;
        wh = Whp + (size_t)dir*512*128; out = fo;
    } else {                          // sent: 32 groups x 2 dirs, T=64
        int s = bg - 4; dir = s & 1; grp = s >> 1; T = 64;
        preBlk = preS + (size_t)(dir*32 + grp) * 64 * 8192;
        wh = Whp + (size_t)(2+dir)*512*128; out = fs;
    }
    const int tid  = threadIdx.x;
    const int wave = tid >> 6, lane = tid & 63;
    const int lr = lane & 15, qr = lane >> 4;
    const int u0 = wave*16 + qr;
    const int t0 = dir ? (T-1) : 0;
    const int dt = dir ? -1 : 1;

    // A-fragments: W_hh rows resident in VGPRs (64 regs) for all T steps
    short8 aw[4][4];
    #pragma unroll
    for (int i = 0; i < 4; ++i)
        #pragma unroll
        for (int kk = 0; kk < 4; ++kk)
            aw[i][kk] = *(const short8*)(wh + (size_t)(wave*64 + i*16 + lr)*128 + kk*32 + qr*8);

    __shared__ __align__(16) u16   hb[2][2048];       // bf16 h exchange (8KB)
    __shared__ __align__(16) float hist[16*2048];     // f32 h history, 16 slots (128KB)
    for (int k = tid; k < 2048; k += 512) hb[0][k] = 0;
    const int rsw = lr << 3;          // 8-u16 (16B) granule XOR for hb
    const int fsw = lr << 2;          // 4-f32 (16B) granule XOR for hist

    // pre prefetch: 4 static slots, step it consumes buf[it&3]; the load issued
    // at step it targets buf[(it+3)&3] -> 3 steps of vmcnt slack, zero reg moves.
    const long pstep = (long)dt * 8192;
    const u16* p = preBlk + (long)t0 * 8192 + tid*16;
    short8 buf[4][2];
    buf[0][0] = *(const short8*)p;            buf[0][1] = *(const short8*)(p + 8);
    buf[1][0] = *(const short8*)(p+pstep);    buf[1][1] = *(const short8*)(p+pstep+8);
    buf[2][0] = *(const short8*)(p+2*pstep);  buf[2][1] = *(const short8*)(p+2*pstep+8);
    p += 3*pstep;

    float cst[4] = {0.f, 0.f, 0.f, 0.f};
    __syncthreads();

#define LSTM_STEP(J, LOADJ) do {                                              \
    short8 bfr[4];                                                            \
    _Pragma("unroll")                                                         \
    for (int kk = 0; kk < 4; ++kk)                                            \
        bfr[kk] = *(const short8*)&hb[(J)&1][lr*128 + ((kk*32 + qr*8) ^ rsw)];\
    buf[LOADJ][0] = *(const short8*)p;                                        \
    buf[LOADJ][1] = *(const short8*)(p + 8);                                  \
    p += pstep;                                                               \
    float* hh = &hist[(ib15 + (J))*2048 + lr*128];                            \
    u16*   hw = &hb[((J) + 1)&1][lr*128];                                     \
    _Pragma("unroll")                                                         \
    for (int i = 0; i < 4; ++i){                                              \
        short8 cs = buf[J][i>>1];                                             \
        const int o = (i&1)*4;                                                \
        f32x4 acc;                                                            \
        acc[0]=b2f((u16)cs[o+0]); acc[1]=b2f((u16)cs[o+1]);                   \
        acc[2]=b2f((u16)cs[o+2]); acc[3]=b2f((u16)cs[o+3]);                   \
        _Pragma("unroll")                                                     \
        for (int kk = 0; kk < 4; ++kk)                                        \
            acc = __builtin_amdgcn_mfma_f32_16x16x32_bf16(aw[i][kk], bfr[kk], acc, 0, 0, 0); \
        float gi=sigm(acc[0]), gf=sigm(acc[1]);                               \
        float gg=tanhf2(acc[2]), go=sigm(acc[3]);                             \
        float c = gf*cst[i] + gi*gg; cst[i]=c;                                \
        float h = go*tanhf2(c);                                               \
        int u = u0 + i*4;                                                     \
        hw[u ^ rsw] = f2b(h);                                                 \
        hh[u ^ fsw] = h;                                                      \
    }                                                                         \
    asm volatile("s_waitcnt lgkmcnt(0)" ::: "memory");                        \
    __builtin_amdgcn_s_barrier();                                             \
} while(0)

    for (int itBase = 0; itBase < T; itBase += 4){
        const int ib15 = itBase & 15;
        LSTM_STEP(0, 3);
        LSTM_STEP(1, 0);
        LSTM_STEP(2, 1);
        LSTM_STEP(3, 2);
        if ((itBase & 7) == 4){
            // coalesced flush of steps [itBase-4, itBase+3] (slots fb..fb+7).
            // Writers' next slots are the OTHER 8 -> no trailing barrier needed.
            const int fBase = itBase - 4;
            const int fb = fBase & 15;
            #pragma unroll
            for (int j2 = 0; j2 < 8; ++j2){
                int lin  = j2*512 + tid;
                int u4   = (lin & 31) * 4;          // f32 col (x4)
                int pair = lin >> 5;
                int s = pair & 7, chn = pair >> 3;
                float4 v = *(const float4*)&hist[(fb + s)*2048 + chn*128 + (u4 ^ (chn << 2))];
                int tt = t0 + dt*(fBase + s);
                *(float4*)(out + ((size_t)(grp*16 + chn)*T + tt)*256 + dir*128 + u4) = v;
            }
        }
    }
#undef LSTM_STEP
}

// ---------------- gate GEMM + blend epilogue ----------------
// gamma = sigmoid([fo|fs] @ gW^T + gb); out = gamma*fo + (1-gamma)*fs
__global__ __launch_bounds__(256) void gemm_gate(
    const u16* __restrict__ gW, const float* __restrict__ gb,
    const float* __restrict__ fo, const float* __restrict__ fs,
    float* __restrict__ out)
{
    __shared__ __align__(16) u16 Asm[128*32];
    __shared__ __align__(16) u16 Bsm[128*32];
    const int m0 = blockIdx.x * 128, n0 = blockIdx.y * 128;
    const int tid = threadIdx.x;
    const int ar = tid >> 2, ch = (tid & 3) * 8;
    const float* af0 = fo + (size_t)(m0 + ar) * 256 + ch;
    const float* af1 = fo + (size_t)(m0 + 64 + ar) * 256 + ch;
    const float* as0 = fs + (size_t)(m0 + ar) * 256 + ch;
    const float* as1 = fs + (size_t)(m0 + 64 + ar) * 256 + ch;
    const u16* bp0 = gW + (size_t)(n0 + ar) * 512 + ch;
    const u16* bp1 = gW + (size_t)(n0 + 64 + ar) * 512 + ch;
    const int lane = tid & 63, wave = tid >> 6;
    const int wm = (wave >> 1) * 64, wn = (wave & 1) * 64;
    const int qr = lane >> 4, lr = lane & 15;
    f32x4 acc[4][4] = {};
    for (int k0 = 0; k0 < 512; k0 += 32){
        __syncthreads();
        const float* s0 = (k0 < 256) ? (af0 + k0) : (as0 + (k0 - 256));
        const float* s1 = (k0 < 256) ? (af1 + k0) : (as1 + (k0 - 256));
        float4 x0 = ((const float4*)s0)[0], x1 = ((const float4*)s0)[1];
        float4 y0 = ((const float4*)s1)[0], y1 = ((const float4*)s1)[1];
        ushort4 a0; a0.x=f2b(x0.x); a0.y=f2b(x0.y); a0.z=f2b(x0.z); a0.w=f2b(x0.w);
        ushort4 a1; a1.x=f2b(x1.x); a1.y=f2b(x1.y); a1.z=f2b(x1.z); a1.w=f2b(x1.w);
        ushort4 b0; b0.x=f2b(y0.x); b0.y=f2b(y0.y); b0.z=f2b(y0.z); b0.w=f2b(y0.w);
        ushort4 b1; b1.x=f2b(y1.x); b1.y=f2b(y1.y); b1.z=f2b(y1.z); b1.w=f2b(y1.w);
        *(ushort4*)&Asm[ar*32 + ch]          = a0;
        *(ushort4*)&Asm[ar*32 + ch + 4]      = a1;
        *(ushort4*)&Asm[(64+ar)*32 + ch]     = b0;
        *(ushort4*)&Asm[(64+ar)*32 + ch + 4] = b1;
        *(short8*)&Bsm[ar*32 + ch]      = *(const short8*)(bp0 + k0);
        *(short8*)&Bsm[(64+ar)*32 + ch] = *(const short8*)(bp1 + k0);
        __syncthreads();
        short8 af[4], bfr[4];
        #pragma unroll
        for (int i = 0; i < 4; ++i){
            af[i]  = *(const short8*)&Asm[(wm + i*16 + lr)*32 + qr*8];
            bfr[i] = *(const short8*)&Bsm[(wn + i*16 + lr)*32 + qr*8];
        }
        #pragma unroll
        for (int i = 0; i < 4; ++i)
            #pragma unroll
            for (int j = 0; j < 4; ++j)
                acc[i][j] = __builtin_amdgcn_mfma_f32_16x16x32_bf16(af[i], bfr[j], acc[i][j], 0, 0, 0);
    }
    #pragma unroll
    for (int j = 0; j < 4; ++j){
        int col = n0 + wn + j*16 + lr;   // 0..255
        float bias = gb[col];
        #pragma unroll
        for (int i = 0; i < 4; ++i){
            #pragma unroll
            for (int r = 0; r < 4; ++r){
                int row = m0 + wm + i*16 + qr*4 + r;
                size_t o = (size_t)row*256 + col;
                float gamma = sigm(acc[i][j][r] + bias);
                out[o] = gamma * fo[o] + (1.f - gamma) * fs[o];
            }
        }
    }
}

extern "C" void kernel_launch(void* const* d_in, const int* in_sizes, int n_in,
                              void* d_out, int out_size, void* d_ws, size_t ws_size,
                              hipStream_t stream)
{
    (void)in_sizes; (void)n_in; (void)out_size; (void)ws_size;
    const int*   wordTok = (const int*)d_in[0];
    const int*   sentTok = (const int*)d_in[1];
    const float* E       = (const float*)d_in[3];
    const float* WihWf   = (const float*)d_in[4];
    const float* WhhWf   = (const float*)d_in[5];
    const float* bWf     = (const float*)d_in[6];
    const float* WihWb   = (const float*)d_in[7];
    const float* WhhWb   = (const float*)d_in[8];
    const float* bWb     = (const float*)d_in[9];
    const float* WihSf   = (const float*)d_in[10];
    const float* WhhSf   = (const float*)d_in[11];
    const float* bSf     = (const float*)d_in[12];
    const float* WihSb   = (const float*)d_in[13];
    const float* WhhSb   = (const float*)d_in[14];
    const float* bSb     = (const float*)d_in[15];
    const float* gateW   = (const float*)d_in[16];
    const float* gateB   = (const float*)d_in[17];
    float* out = (float*)d_out;

    char* w = (char*)d_ws;
    u16* Eb   = (u16*)w;  w += (size_t)30522*768*2;
    u16* Ww   = (u16*)w;  w += (size_t)1024*768*2;
    u16* Ws_  = (u16*)w;  w += (size_t)1024*768*2;
    u16* gWb  = (u16*)w;  w += (size_t)256*512*2;
    u16* preW = (u16*)w;  w += (size_t)32768*1024*2;
    u16* preS = (u16*)w;  w += (size_t)32768*1024*2;
    float* fo = (float*)w; w += (size_t)32768*256*4;
    float* fs = (float*)w; w += (size_t)32768*256*4;
    u16* Whp  = (u16*)w;  w += (size_t)4*512*128*2;

    const int nE4 = 30522*768/4;
    cvt_bf16<<<(nE4+255)/256, 256, 0, stream>>>(E, Eb, nE4);
    cvt_wih_perm<<<512, 192, 0, stream>>>(WihWf, Ww);
    cvt_wih_perm<<<512, 192, 0, stream>>>(WihWb, Ww + 512*768);
    cvt_wih_perm<<<512, 192, 0, stream>>>(WihSf, Ws_);
    cvt_wih_perm<<<512, 192, 0, stream>>>(WihSb, Ws_ + 512*768);
    const int nG4 = 256*512/4;
    cvt_bf16<<<(nG4+255)/256, 256, 0, stream>>>(gateW, gWb, nG4);
    cvt_whh_perm<<<64, 256, 0, stream>>>(WhhWf, Whp);
    cvt_whh_perm<<<64, 256, 0, stream>>>(WhhWb, Whp + 512*128);
    cvt_whh_perm<<<64, 256, 0, stream>>>(WhhSf, Whp + 2*512*128);
    cvt_whh_perm<<<64, 256, 0, stream>>>(WhhSb, Whp + 3*512*128);

    gemm_embed<<<dim3(256,8), 256, 0, stream>>>(Eb, wordTok, Ww, bWf, bWb, preW, 0);
    gemm_embed<<<dim3(256,8), 256, 0, stream>>>(Eb, sentTok, Ws_, bSf, bSb, preS, 1);
    lstm_rec<<<68, 512, 0, stream>>>(preW, preS, Whp, fo, fs);
    gemm_gate<<<dim3(256,2), 256, 0, stream>>>(gWb, gateB, fo, fs, out);
}

// Round 5
// 1934.812 us; speedup vs baseline: 1.7635x; 1.0437x over previous
//
#include <hip/hip_runtime.h>

typedef unsigned short u16;
typedef __attribute__((ext_vector_type(8))) short short8;
typedef __attribute__((ext_vector_type(4))) float f32x4;

__device__ __forceinline__ u16 f2b(float f){
    unsigned u = __builtin_bit_cast(unsigned, f);
    u += 0x7fffu + ((u >> 16) & 1u);   // RNE
    return (u16)(u >> 16);
}
__device__ __forceinline__ float b2f(u16 s){
    unsigned u = ((unsigned)s) << 16;
    return __builtin_bit_cast(float, u);
}
__device__ __forceinline__ float sigm(float x){ return 1.f/(1.f + __expf(-x)); }
// branch-free tanh: 1 - 2/(1+e^{2x})
__device__ __forceinline__ float tanhf2(float x){
    float e = __expf(2.f * x);
    return 1.f - 2.f/(1.f + e);
}

// ---------------- fp32 -> bf16 conversion ----------------
__global__ __launch_bounds__(256) void cvt_bf16(const float* __restrict__ s,
                                                u16* __restrict__ d, int n4){
    int i = blockIdx.x*256 + threadIdx.x;
    if (i < n4){
        float4 v = ((const float4*)s)[i];
        ushort4 o;
        o.x = f2b(v.x); o.y = f2b(v.y); o.z = f2b(v.z); o.w = f2b(v.w);
        ((ushort4*)d)[i] = o;
    }
}

// ---- W_ih cvt with row permutation: out row (unit*4+gate) = in row (gate*128+unit) ----
__global__ __launch_bounds__(192) void cvt_wih_perm(const float* __restrict__ s,
                                                    u16* __restrict__ d){
    int r = blockIdx.x;               // 0..511 input row
    int j = threadIdx.x;              // 0..191 float4 within row
    int g = r >> 7, u = r & 127;
    int ro = u * 4 + g;
    float4 v = ((const float4*)(s + (size_t)r * 768))[j];
    ushort4 o;
    o.x = f2b(v.x); o.y = f2b(v.y); o.z = f2b(v.z); o.w = f2b(v.w);
    ((ushort4*)(d + (size_t)ro * 768))[j] = o;
}

// ---- W_hh cvt with the same row permutation, 128 cols, bf16 out ----
__global__ __launch_bounds__(256) void cvt_whh_perm(const float* __restrict__ s,
                                                    u16* __restrict__ d){
    int idx = blockIdx.x*256 + threadIdx.x;   // 0..16383
    if (idx >= 512*32) return;
    int r = idx >> 5, j = idx & 31;           // row, float4 within row
    int g = r >> 7, u = r & 127;
    int ro = u * 4 + g;
    float4 v = ((const float4*)(s + (size_t)r * 128))[j];
    ushort4 o;
    o.x = f2b(v.x); o.y = f2b(v.y); o.z = f2b(v.z); o.w = f2b(v.w);
    ((ushort4*)(d + (size_t)ro * 128))[j] = o;
}

// ---------------- embedding-gather + input projection GEMM ----------------
// pre-activations written in the LANE-EXACT layout the 1024-thread lstm_rec consumes:
//   idx = ((blk*Tdim + t) * 1024 + tidL) * 8 + iL*4 + g   (u16 units)
// lstm lane (waveL 0..15, qrL 0..3, lrL=chain&15): tidL = waveL*64+qrL*16+lrL,
// gate-row p = u*4+g, u = waveL*8 + iL*4 + qrL  (iL in 0..1).
__global__ __launch_bounds__(256) void gemm_embed(
    const u16* __restrict__ E, const int* __restrict__ tok,
    const u16* __restrict__ Wt, const float* __restrict__ bf_,
    const float* __restrict__ bb_, u16* __restrict__ pre, int sentMode)
{
    __shared__ __align__(16) u16 Asm[128*32];
    __shared__ __align__(16) u16 Bsm[128*32];
    const int m0 = blockIdx.x * 128, n0 = blockIdx.y * 128;
    const int tid = threadIdx.x;
    const int ar = tid >> 2, ch = (tid & 3) * 8;
    const u16* ap0 = E + (size_t)tok[m0 + ar] * 768 + ch;
    const u16* ap1 = E + (size_t)tok[m0 + 64 + ar] * 768 + ch;
    const u16* bp0 = Wt + (size_t)(n0 + ar) * 768 + ch;
    const u16* bp1 = Wt + (size_t)(n0 + 64 + ar) * 768 + ch;
    const int lane = tid & 63, wave = tid >> 6;
    const int wm = (wave >> 1) * 64, wn = (wave & 1) * 64;
    const int qr = lane >> 4, lr = lane & 15;
    f32x4 acc[4][4] = {};
    for (int k0 = 0; k0 < 768; k0 += 32){
        __syncthreads();
        *(short8*)&Asm[ar*32 + ch]      = *(const short8*)(ap0 + k0);
        *(short8*)&Asm[(64+ar)*32 + ch] = *(const short8*)(ap1 + k0);
        *(short8*)&Bsm[ar*32 + ch]      = *(const short8*)(bp0 + k0);
        *(short8*)&Bsm[(64+ar)*32 + ch] = *(const short8*)(bp1 + k0);
        __syncthreads();
        short8 af[4], bfr[4];
        #pragma unroll
        for (int i = 0; i < 4; ++i){
            af[i]  = *(const short8*)&Asm[(wm + i*16 + lr)*32 + qr*8];
            bfr[i] = *(const short8*)&Bsm[(wn + i*16 + lr)*32 + qr*8];
        }
        #pragma unroll
        for (int i = 0; i < 4; ++i)
            #pragma unroll
            for (int j = 0; j < 4; ++j)
                acc[i][j] = __builtin_amdgcn_mfma_f32_16x16x32_bf16(af[i], bfr[j], acc[i][j], 0, 0, 0);
    }
    #pragma unroll
    for (int j = 0; j < 4; ++j){
        int col = n0 + wn + j*16 + lr;
        int dirO = col >> 9, pcol = col & 511;
        int uu = pcol >> 2, gg = pcol & 3;
        float bias = (dirO ? bb_ : bf_)[gg*128 + uu];
        int tidBase = ((uu >> 3) << 6) | ((uu & 3) << 4);   // waveL*64 + qrL*16
        int ig4 = (((uu >> 2) & 1) << 2) | gg;              // iL*4 + g
        #pragma unroll
        for (int i = 0; i < 4; ++i){
            #pragma unroll
            for (int r = 0; r < 4; ++r){
                int mrow = m0 + wm + i*16 + qr*4 + r;
                int chain, t, blk, Tdim;
                if (sentMode){ chain = mrow >> 6;  t = mrow & 63;   blk = dirO*32 + (chain >> 4); Tdim = 64; }
                else         { chain = mrow >> 10; t = mrow & 1023; blk = dirO*2  + (chain >> 4); Tdim = 1024; }
                size_t idx = (((size_t)blk * Tdim + t) * 1024 + (tidBase + (chain & 15))) * 8 + ig4;
                pre[idx] = f2b(acc[i][j][r] + bias);
            }
        }
    }
}

// ---------------- batched MFMA LSTM recurrence ----------------
// One block per (direction, group of 16 chains). 1024 threads = 16 waves;
// each wave owns 32 gate-rows -> aw = 2x4 short8 = 32 VGPRs, total live
// pressure ~110 VGPR: W_hh fragments stay RESIDENT without fighting the
// allocator (512-thr versions compiled to 84-96 VGPR with per-step W reloads).
// Per step: C[512 gate-rows x 16 chains] = W_hh_perm[512x128] @ h[16x128]^T.
// Lane holds gates (i,f,g,o) of units u = wave*8 + i*4 + qr (i=0..1), chain lr.
// Step barrier: bare s_waitcnt lgkmcnt(0) (NO "memory" clobber!) + raw s_barrier.
// The clobbered form made the waitcnt pass treat the asm as reading all memory
// -> per-step vmcnt(0) drain of the pre prefetch (~900cyc HBM) = the invariant
// ~3.5k-cyc/step floor of rounds 0-4.
__global__ __launch_bounds__(1024, 1) void lstm_rec(
    const u16* __restrict__ preW, const u16* __restrict__ preS,
    const u16* __restrict__ Whp,     // [4][512][128] bf16: wordF, wordB, sentF, sentB
    float* __restrict__ fo, float* __restrict__ fs)
{
    const int bg = blockIdx.x;
    const u16* preBlk; const u16* wh; float* out;
    int T, dir, grp;
    if (bg < 4){                      // word: 2 groups x 2 dirs, T=1024
        dir = bg & 1; grp = bg >> 1; T = 1024;
        preBlk = preW + (size_t)(dir*2 + grp) * 1024 * 8192;
        wh = Whp + (size_t)dir*512*128; out = fo;
    } else {                          // sent: 32 groups x 2 dirs, T=64
        int s = bg - 4; dir = s & 1; grp = s >> 1; T = 64;
        preBlk = preS + (size_t)(dir*32 + grp) * 64 * 8192;
        wh = Whp + (size_t)(2+dir)*512*128; out = fs;
    }
    const int tid  = threadIdx.x;
    const int wave = tid >> 6, lane = tid & 63;
    const int lr = lane & 15, qr = lane >> 4;
    const int u0 = wave*8 + qr;
    const int t0 = dir ? (T-1) : 0;
    const int dt = dir ? -1 : 1;

    // A-fragments: 32 W_hh rows per wave, resident in 32 VGPRs for all T steps
    short8 aw[2][4];
    #pragma unroll
    for (int i = 0; i < 2; ++i)
        #pragma unroll
        for (int kk = 0; kk < 4; ++kk)
            aw[i][kk] = *(const short8*)(wh + (size_t)(wave*32 + i*16 + lr)*128 + kk*32 + qr*8);

    __shared__ __align__(16) u16   hb[2][2048];       // bf16 h exchange (8KB)
    __shared__ __align__(16) float hist[16*2048];     // f32 h history, 16 slots (128KB)
    for (int k = tid; k < 2048; k += 1024) hb[0][k] = 0;
    const int rsw = lr << 3;          // 8-u16 (16B) granule XOR for hb
    const int fsw = lr << 2;          // 4-f32 (16B) granule XOR for hist

    // pre prefetch: 4 static slots; step it consumes buf[it&3], load issued at
    // step it targets buf[(it+3)&3] -> 3 steps of counted-vmcnt slack.
    const long pstep = (long)dt * 8192;
    const u16* p = preBlk + (long)t0 * 8192 + tid*8;
    short8 buf[4];
    buf[0] = *(const short8*)p;
    buf[1] = *(const short8*)(p + pstep);
    buf[2] = *(const short8*)(p + 2*pstep);
    p += 3*pstep;

    float cst[2] = {0.f, 0.f};
    __syncthreads();

#define LSTM_STEP(J, LOADJ) do {                                              \
    short8 bfr[4];                                                            \
    _Pragma("unroll")                                                         \
    for (int kk = 0; kk < 4; ++kk)                                            \
        bfr[kk] = *(const short8*)&hb[(J)&1][lr*128 + ((kk*32 + qr*8) ^ rsw)];\
    buf[LOADJ] = *(const short8*)p;                                           \
    p += pstep;                                                               \
    float* hh = &hist[(ib15 + (J))*2048 + lr*128];                            \
    u16*   hw = &hb[((J) + 1)&1][lr*128];                                     \
    short8 cs = buf[J];                                                       \
    _Pragma("unroll")                                                         \
    for (int i = 0; i < 2; ++i){                                              \
        const int o = i*4;                                                    \
        f32x4 acc;                                                            \
        acc[0]=b2f((u16)cs[o+0]); acc[1]=b2f((u16)cs[o+1]);                   \
        acc[2]=b2f((u16)cs[o+2]); acc[3]=b2f((u16)cs[o+3]);                   \
        _Pragma("unroll")                                                     \
        for (int kk = 0; kk < 4; ++kk)                                        \
            acc = __builtin_amdgcn_mfma_f32_16x16x32_bf16(aw[i][kk], bfr[kk], acc, 0, 0, 0); \
        float gi=sigm(acc[0]), gf=sigm(acc[1]);                               \
        float gg=tanhf2(acc[2]), go=sigm(acc[3]);                             \
        float c = gf*cst[i] + gi*gg; cst[i]=c;                                \
        float h = go*tanhf2(c);                                               \
        int u = u0 + i*4;                                                     \
        hw[u ^ rsw] = f2b(h);                                                 \
        hh[u ^ fsw] = h;                                                      \
    }                                                                         \
    asm volatile("s_waitcnt lgkmcnt(0)");                                     \
    __builtin_amdgcn_s_barrier();                                             \
} while(0)

    for (int itBase = 0; itBase < T; itBase += 4){
        const int ib15 = itBase & 15;
        LSTM_STEP(0, 3);
        LSTM_STEP(1, 0);
        LSTM_STEP(2, 1);
        LSTM_STEP(3, 2);
        if ((itBase & 7) == 4){
            // coalesced flush of steps [itBase-4, itBase+3] (slots fb..fb+7).
            // Writers' next 8 slots are the OTHER half -> no trailing barrier.
            const int fBase = itBase - 4;
            const int fb = fBase & 15;
            #pragma unroll
            for (int j2 = 0; j2 < 4; ++j2){
                int lin  = j2*1024 + tid;
                int u4   = (lin & 31) * 4;          // f32 col (x4)
                int pair = lin >> 5;
                int s = pair & 7, chn = pair >> 3;
                float4 v = *(const float4*)&hist[(fb + s)*2048 + chn*128 + (u4 ^ (chn << 2))];
                int tt = t0 + dt*(fBase + s);
                *(float4*)(out + ((size_t)(grp*16 + chn)*T + tt)*256 + dir*128 + u4) = v;
            }
        }
    }
#undef LSTM_STEP
}

// ---------------- gate GEMM + blend epilogue ----------------
// gamma = sigmoid([fo|fs] @ gW^T + gb); out = gamma*fo + (1-gamma)*fs
__global__ __launch_bounds__(256) void gemm_gate(
    const u16* __restrict__ gW, const float* __restrict__ gb,
    const float* __restrict__ fo, const float* __restrict__ fs,
    float* __restrict__ out)
{
    __shared__ __align__(16) u16 Asm[128*32];
    __shared__ __align__(16) u16 Bsm[128*32];
    const int m0 = blockIdx.x * 128, n0 = blockIdx.y * 128;
    const int tid = threadIdx.x;
    const int ar = tid >> 2, ch = (tid & 3) * 8;
    const float* af0 = fo + (size_t)(m0 + ar) * 256 + ch;
    const float* af1 = fo + (size_t)(m0 + 64 + ar) * 256 + ch;
    const float* as0 = fs + (size_t)(m0 + ar) * 256 + ch;
    const float* as1 = fs + (size_t)(m0 + 64 + ar) * 256 + ch;
    const u16* bp0 = gW + (size_t)(n0 + ar) * 512 + ch;
    const u16* bp1 = gW + (size_t)(n0 + 64 + ar) * 512 + ch;
    const int lane = tid & 63, wave = tid >> 6;
    const int wm = (wave >> 1) * 64, wn = (wave & 1) * 64;
    const int qr = lane >> 4, lr = lane & 15;
    f32x4 acc[4][4] = {};
    for (int k0 = 0; k0 < 512; k0 += 32){
        __syncthreads();
        const float* s0 = (k0 < 256) ? (af0 + k0) : (as0 + (k0 - 256));
        const float* s1 = (k0 < 256) ? (af1 + k0) : (as1 + (k0 - 256));
        float4 x0 = ((const float4*)s0)[0], x1 = ((const float4*)s0)[1];
        float4 y0 = ((const float4*)s1)[0], y1 = ((const float4*)s1)[1];
        ushort4 a0; a0.x=f2b(x0.x); a0.y=f2b(x0.y); a0.z=f2b(x0.z); a0.w=f2b(x0.w);
        ushort4 a1; a1.x=f2b(x1.x); a1.y=f2b(x1.y); a1.z=f2b(x1.z); a1.w=f2b(x1.w);
        ushort4 b0; b0.x=f2b(y0.x); b0.y=f2b(y0.y); b0.z=f2b(y0.z); b0.w=f2b(y0.w);
        ushort4 b1; b1.x=f2b(y1.x); b1.y=f2b(y1.y); b1.z=f2b(y1.z); b1.w=f2b(y1.w);
        *(ushort4*)&Asm[ar*32 + ch]          = a0;
        *(ushort4*)&Asm[ar*32 + ch + 4]      = a1;
        *(ushort4*)&Asm[(64+ar)*32 + ch]     = b0;
        *(ushort4*)&Asm[(64+ar)*32 + ch + 4] = b1;
        *(short8*)&Bsm[ar*32 + ch]      = *(const short8*)(bp0 + k0);
        *(short8*)&Bsm[(64+ar)*32 + ch] = *(const short8*)(bp1 + k0);
        __syncthreads();
        short8 af[4], bfr[4];
        #pragma unroll
        for (int i = 0; i < 4; ++i){
            af[i]  = *(const short8*)&Asm[(wm + i*16 + lr)*32 + qr*8];
            bfr[i] = *(const short8*)&Bsm[(wn + i*16 + lr)*32 + qr*8];
        }
        #pragma unroll
        for (int i = 0; i < 4; ++i)
            #pragma unroll
            for (int j = 0; j < 4; ++j)
                acc[i][j] = __builtin_amdgcn_mfma_f32_16x16x32_bf16(af[i], bfr[j], acc[i][j], 0, 0, 0);
    }
    #pragma unroll
    for (int j = 0; j < 4; ++j){
        int col = n0 + wn + j*16 + lr;   // 0..255
        float bias = gb[col];
        #pragma unroll
        for (int i = 0; i < 4; ++i){
            #pragma unroll
            for (int r = 0; r < 4; ++r){
                int row = m0 + wm + i*16 + qr*4 + r;
                size_t o = (size_t)row*256 + col;
                float gamma = sigm(acc[i][j][r] + bias);
                out[o] = gamma * fo[o] + (1.f - gamma) * fs[o];
            }
        }
    }
}

extern "C" void kernel_launch(void* const* d_in, const int* in_sizes, int n_in,
                              void* d_out, int out_size, void* d_ws, size_t ws_size,
                              hipStream_t stream)
{
    (void)in_sizes; (void)n_in; (void)out_size; (void)ws_size;
    const int*   wordTok = (const int*)d_in[0];
    const int*   sentTok = (const int*)d_in[1];
    const float* E       = (const float*)d_in[3];
    const float* WihWf   = (const float*)d_in[4];
    const float* WhhWf   = (const float*)d_in[5];
    const float* bWf     = (const float*)d_in[6];
    const float* WihWb   = (const float*)d_in[7];
    const float* WhhWb   = (const float*)d_in[8];
    const float* bWb     = (const float*)d_in[9];
    const float* WihSf   = (const float*)d_in[10];
    const float* WhhSf   = (const float*)d_in[11];
    const float* bSf     = (const float*)d_in[12];
    const float* WihSb   = (const float*)d_in[13];
    const float* WhhSb   = (const float*)d_in[14];
    const float* bSb     = (const float*)d_in[15];
    const float* gateW   = (const float*)d_in[16];
    const float* gateB   = (const float*)d_in[17];
    float* out = (float*)d_out;

    char* w = (char*)d_ws;
    u16* Eb   = (u16*)w;  w += (size_t)30522*768*2;
    u16* Ww   = (u16*)w;  w += (size_t)1024*768*2;
    u16* Ws_  = (u16*)w;  w += (size_t)1024*768*2;
    u16* gWb  = (u16*)w;  w += (size_t)256*512*2;
    u16* preW = (u16*)w;  w += (size_t)32768*1024*2;
    u16* preS = (u16*)w;  w += (size_t)32768*1024*2;
    float* fo = (float*)w; w += (size_t)32768*256*4;
    float* fs = (float*)w; w += (size_t)32768*256*4;
    u16* Whp  = (u16*)w;  w += (size_t)4*512*128*2;

    const int nE4 = 30522*768/4;
    cvt_bf16<<<(nE4+255)/256, 256, 0, stream>>>(E, Eb, nE4);
    cvt_wih_perm<<<512, 192, 0, stream>>>(WihWf, Ww);
    cvt_wih_perm<<<512, 192, 0, stream>>>(WihWb, Ww + 512*768);
    cvt_wih_perm<<<512, 192, 0, stream>>>(WihSf, Ws_);
    cvt_wih_perm<<<512, 192, 0, stream>>>(WihSb, Ws_ + 512*768);
    const int nG4 = 256*512/4;
    cvt_bf16<<<(nG4+255)/256, 256, 0, stream>>>(gateW, gWb, nG4);
    cvt_whh_perm<<<64, 256, 0, stream>>>(WhhWf, Whp);
    cvt_whh_perm<<<64, 256, 0, stream>>>(WhhWb, Whp + 512*128);
    cvt_whh_perm<<<64, 256, 0, stream>>>(WhhSf, Whp + 2*512*128);
    cvt_whh_perm<<<64, 256, 0, stream>>>(WhhSb, Whp + 3*512*128);

    gemm_embed<<<dim3(256,8), 256, 0, stream>>>(Eb, wordTok, Ww, bWf, bWb, preW, 0);
    gemm_embed<<<dim3(256,8), 256, 0, stream>>>(Eb, sentTok, Ws_, bSf, bSb, preS, 1);
    lstm_rec<<<68, 1024, 0, stream>>>(preW, preS, Whp, fo, fs);
    gemm_gate<<<dim3(256,2), 256, 0, stream>>>(gWb, gateB, fo, fs, out);
}

// Round 6
// 1932.378 us; speedup vs baseline: 1.7658x; 1.0013x over previous
//
#include <hip/hip_runtime.h>

typedef unsigned short u16;
typedef __attribute__((ext_vector_type(8))) short short8;
typedef __attribute__((ext_vector_type(4))) float f32x4;

__device__ __forceinline__ u16 f2b(float f){
    unsigned u = __builtin_bit_cast(unsigned, f);
    u += 0x7fffu + ((u >> 16) & 1u);   // RNE
    return (u16)(u >> 16);
}
__device__ __forceinline__ float b2f(u16 s){
    unsigned u = ((unsigned)s) << 16;
    return __builtin_bit_cast(float, u);
}
__device__ __forceinline__ float sigm(float x){ return 1.f/(1.f + __expf(-x)); }
// branch-free tanh: 1 - 2/(1+e^{2x})
__device__ __forceinline__ float tanhf2(float x){
    float e = __expf(2.f * x);
    return 1.f - 2.f/(1.f + e);
}
// pinned 16B global load: volatile asm cannot be sunk/rematerialized into the
// step loop by the register allocator -> result MUST stay VGPR-resident.
__device__ __forceinline__ short8 gld_pin(const u16* p){
    short8 r;
    asm volatile("global_load_dwordx4 %0, %1, off" : "=v"(r) : "v"(p));
    return r;
}

// ---------------- fp32 -> bf16 conversion ----------------
__global__ __launch_bounds__(256) void cvt_bf16(const float* __restrict__ s,
                                                u16* __restrict__ d, int n4){
    int i = blockIdx.x*256 + threadIdx.x;
    if (i < n4){
        float4 v = ((const float4*)s)[i];
        ushort4 o;
        o.x = f2b(v.x); o.y = f2b(v.y); o.z = f2b(v.z); o.w = f2b(v.w);
        ((ushort4*)d)[i] = o;
    }
}

// ---- W_ih cvt with row permutation: out row (unit*4+gate) = in row (gate*128+unit) ----
__global__ __launch_bounds__(192) void cvt_wih_perm(const float* __restrict__ s,
                                                    u16* __restrict__ d){
    int r = blockIdx.x;               // 0..511 input row
    int j = threadIdx.x;              // 0..191 float4 within row
    int g = r >> 7, u = r & 127;
    int ro = u * 4 + g;
    float4 v = ((const float4*)(s + (size_t)r * 768))[j];
    ushort4 o;
    o.x = f2b(v.x); o.y = f2b(v.y); o.z = f2b(v.z); o.w = f2b(v.w);
    ((ushort4*)(d + (size_t)ro * 768))[j] = o;
}

// ---- W_hh cvt with the same row permutation, 128 cols, bf16 out ----
__global__ __launch_bounds__(256) void cvt_whh_perm(const float* __restrict__ s,
                                                    u16* __restrict__ d){
    int idx = blockIdx.x*256 + threadIdx.x;   // 0..16383
    if (idx >= 512*32) return;
    int r = idx >> 5, j = idx & 31;           // row, float4 within row
    int g = r >> 7, u = r & 127;
    int ro = u * 4 + g;
    float4 v = ((const float4*)(s + (size_t)r * 128))[j];
    ushort4 o;
    o.x = f2b(v.x); o.y = f2b(v.y); o.z = f2b(v.z); o.w = f2b(v.w);
    ((ushort4*)(d + (size_t)ro * 128))[j] = o;
}

// ---------------- embedding-gather + input projection GEMM ----------------
// pre-activations written in the LANE-EXACT layout the 1024-thread lstm_rec consumes:
//   idx = ((blk*Tdim + t) * 1024 + tidL) * 8 + iL*4 + g   (u16 units)
// lstm lane (waveL 0..15, qrL 0..3, lrL=chain&15): tidL = waveL*64+qrL*16+lrL,
// gate-row p = u*4+g, u = waveL*8 + iL*4 + qrL  (iL in 0..1).
__global__ __launch_bounds__(256) void gemm_embed(
    const u16* __restrict__ E, const int* __restrict__ tok,
    const u16* __restrict__ Wt, const float* __restrict__ bf_,
    const float* __restrict__ bb_, u16* __restrict__ pre, int sentMode)
{
    __shared__ __align__(16) u16 Asm[128*32];
    __shared__ __align__(16) u16 Bsm[128*32];
    const int m0 = blockIdx.x * 128, n0 = blockIdx.y * 128;
    const int tid = threadIdx.x;
    const int ar = tid >> 2, ch = (tid & 3) * 8;
    const u16* ap0 = E + (size_t)tok[m0 + ar] * 768 + ch;
    const u16* ap1 = E + (size_t)tok[m0 + 64 + ar] * 768 + ch;
    const u16* bp0 = Wt + (size_t)(n0 + ar) * 768 + ch;
    const u16* bp1 = Wt + (size_t)(n0 + 64 + ar) * 768 + ch;
    const int lane = tid & 63, wave = tid >> 6;
    const int wm = (wave >> 1) * 64, wn = (wave & 1) * 64;
    const int qr = lane >> 4, lr = lane & 15;
    f32x4 acc[4][4] = {};
    for (int k0 = 0; k0 < 768; k0 += 32){
        __syncthreads();
        *(short8*)&Asm[ar*32 + ch]      = *(const short8*)(ap0 + k0);
        *(short8*)&Asm[(64+ar)*32 + ch] = *(const short8*)(ap1 + k0);
        *(short8*)&Bsm[ar*32 + ch]      = *(const short8*)(bp0 + k0);
        *(short8*)&Bsm[(64+ar)*32 + ch] = *(const short8*)(bp1 + k0);
        __syncthreads();
        short8 af[4], bfr[4];
        #pragma unroll
        for (int i = 0; i < 4; ++i){
            af[i]  = *(const short8*)&Asm[(wm + i*16 + lr)*32 + qr*8];
            bfr[i] = *(const short8*)&Bsm[(wn + i*16 + lr)*32 + qr*8];
        }
        #pragma unroll
        for (int i = 0; i < 4; ++i)
            #pragma unroll
            for (int j = 0; j < 4; ++j)
                acc[i][j] = __builtin_amdgcn_mfma_f32_16x16x32_bf16(af[i], bfr[j], acc[i][j], 0, 0, 0);
    }
    #pragma unroll
    for (int j = 0; j < 4; ++j){
        int col = n0 + wn + j*16 + lr;
        int dirO = col >> 9, pcol = col & 511;
        int uu = pcol >> 2, gg = pcol & 3;
        float bias = (dirO ? bb_ : bf_)[gg*128 + uu];
        int tidBase = ((uu >> 3) << 6) | ((uu & 3) << 4);   // waveL*64 + qrL*16
        int ig4 = (((uu >> 2) & 1) << 2) | gg;              // iL*4 + g
        #pragma unroll
        for (int i = 0; i < 4; ++i){
            #pragma unroll
            for (int r = 0; r < 4; ++r){
                int mrow = m0 + wm + i*16 + qr*4 + r;
                int chain, t, blk, Tdim;
                if (sentMode){ chain = mrow >> 6;  t = mrow & 63;   blk = dirO*32 + (chain >> 4); Tdim = 64; }
                else         { chain = mrow >> 10; t = mrow & 1023; blk = dirO*2  + (chain >> 4); Tdim = 1024; }
                size_t idx = (((size_t)blk * Tdim + t) * 1024 + (tidBase + (chain & 15))) * 8 + ig4;
                pre[idx] = f2b(acc[i][j][r] + bias);
            }
        }
    }
}

// ---------------- batched MFMA LSTM recurrence ----------------
// One block per (direction, group of 16 chains). 1024 threads = 16 waves.
// ROOT CAUSE (r3-r5): the RA kept rematerializing the W_hh fragment loads
// INSIDE the step loop (VGPR counts 84/96/56 -- too small to hold aw at all),
// refetching the full 128KB W panel from L2 every step: 128KB / ~56 B/cyc/CU
// ~= 2300 cyc/step = the invariant floor. Two deterministic fixes:
//  (1) amdgpu_waves_per_eu(4,4): LDS (139KB) already caps the CU at 1 block
//      = 4 waves/EU; telling the RA that unlocks the honest 128-VGPR budget.
//  (2) aw loaded via volatile-asm global_load_dwordx4 (gld_pin): cannot be
//      sunk or rematerialized -> stays VGPR-resident for all T steps.
__global__ __launch_bounds__(1024)
__attribute__((amdgpu_waves_per_eu(4, 4)))
void lstm_rec(
    const u16* __restrict__ preW, const u16* __restrict__ preS,
    const u16* __restrict__ Whp,     // [4][512][128] bf16: wordF, wordB, sentF, sentB
    float* __restrict__ fo, float* __restrict__ fs)
{
    const int bg = blockIdx.x;
    const u16* preBlk; const u16* wh; float* out;
    int T, dir, grp;
    if (bg < 4){                      // word: 2 groups x 2 dirs, T=1024
        dir = bg & 1; grp = bg >> 1; T = 1024;
        preBlk = preW + (size_t)(dir*2 + grp) * 1024 * 8192;
        wh = Whp + (size_t)dir*512*128; out = fo;
    } else {                          // sent: 32 groups x 2 dirs, T=64
        int s = bg - 4; dir = s & 1; grp = s >> 1; T = 64;
        preBlk = preS + (size_t)(dir*32 + grp) * 64 * 8192;
        wh = Whp + (size_t)(2+dir)*512*128; out = fs;
    }
    const int tid  = threadIdx.x;
    const int wave = tid >> 6, lane = tid & 63;
    const int lr = lane & 15, qr = lane >> 4;
    const int u0 = wave*8 + qr;
    const int t0 = dir ? (T-1) : 0;
    const int dt = dir ? -1 : 1;

    // A-fragments: 32 W_hh rows per wave, PINNED in 32 VGPRs for all T steps
    short8 aw[2][4];
    #pragma unroll
    for (int i = 0; i < 2; ++i)
        #pragma unroll
        for (int kk = 0; kk < 4; ++kk)
            aw[i][kk] = gld_pin(wh + (size_t)(wave*32 + i*16 + lr)*128 + kk*32 + qr*8);
    asm volatile("s_waitcnt vmcnt(0)");
    __builtin_amdgcn_sched_barrier(0);

    __shared__ __align__(16) u16   hb[2][2048];       // bf16 h exchange (8KB)
    __shared__ __align__(16) float hist[16*2048];     // f32 h history, 16 slots (128KB)
    for (int k = tid; k < 2048; k += 1024) hb[0][k] = 0;
    const int rsw = lr << 3;          // 8-u16 (16B) granule XOR for hb
    const int fsw = lr << 2;          // 4-f32 (16B) granule XOR for hist

    // pre prefetch: 4 static slots; step it consumes buf[it&3], load issued at
    // step it targets buf[(it+3)&3] -> 3 steps of counted-vmcnt slack.
    const long pstep = (long)dt * 8192;
    const u16* p = preBlk + (long)t0 * 8192 + tid*8;
    short8 buf[4];
    buf[0] = *(const short8*)p;
    buf[1] = *(const short8*)(p + pstep);
    buf[2] = *(const short8*)(p + 2*pstep);
    p += 3*pstep;

    float cst[2] = {0.f, 0.f};
    __syncthreads();

#define LSTM_STEP(J, LOADJ) do {                                              \
    short8 bfr[4];                                                            \
    _Pragma("unroll")                                                         \
    for (int kk = 0; kk < 4; ++kk)                                            \
        bfr[kk] = *(const short8*)&hb[(J)&1][lr*128 + ((kk*32 + qr*8) ^ rsw)];\
    buf[LOADJ] = *(const short8*)p;                                           \
    p += pstep;                                                               \
    float* hh = &hist[(ib15 + (J))*2048 + lr*128];                            \
    u16*   hw = &hb[((J) + 1)&1][lr*128];                                     \
    short8 cs = buf[J];                                                       \
    _Pragma("unroll")                                                         \
    for (int i = 0; i < 2; ++i){                                              \
        const int o = i*4;                                                    \
        f32x4 acc;                                                            \
        acc[0]=b2f((u16)cs[o+0]); acc[1]=b2f((u16)cs[o+1]);                   \
        acc[2]=b2f((u16)cs[o+2]); acc[3]=b2f((u16)cs[o+3]);                   \
        _Pragma("unroll")                                                     \
        for (int kk = 0; kk < 4; ++kk)                                        \
            acc = __builtin_amdgcn_mfma_f32_16x16x32_bf16(aw[i][kk], bfr[kk], acc, 0, 0, 0); \
        float gi=sigm(acc[0]), gf=sigm(acc[1]);                               \
        float gg=tanhf2(acc[2]), go=sigm(acc[3]);                             \
        float c = gf*cst[i] + gi*gg; cst[i]=c;                                \
        float h = go*tanhf2(c);                                               \
        int u = u0 + i*4;                                                     \
        hw[u ^ rsw] = f2b(h);                                                 \
        hh[u ^ fsw] = h;                                                      \
    }                                                                         \
    asm volatile("s_waitcnt lgkmcnt(0)");                                     \
    __builtin_amdgcn_s_barrier();                                             \
} while(0)

    for (int itBase = 0; itBase < T; itBase += 4){
        const int ib15 = itBase & 15;
        LSTM_STEP(0, 3);
        LSTM_STEP(1, 0);
        LSTM_STEP(2, 1);
        LSTM_STEP(3, 2);
        if ((itBase & 7) == 4){
            // coalesced flush of steps [itBase-4, itBase+3] (slots fb..fb+7).
            // Writers' next 8 slots are the OTHER half -> no trailing barrier.
            const int fBase = itBase - 4;
            const int fb = fBase & 15;
            #pragma unroll
            for (int j2 = 0; j2 < 4; ++j2){
                int lin  = j2*1024 + tid;
                int u4   = (lin & 31) * 4;          // f32 col (x4)
                int pair = lin >> 5;
                int s = pair & 7, chn = pair >> 3;
                float4 v = *(const float4*)&hist[(fb + s)*2048 + chn*128 + (u4 ^ (chn << 2))];
                int tt = t0 + dt*(fBase + s);
                *(float4*)(out + ((size_t)(grp*16 + chn)*T + tt)*256 + dir*128 + u4) = v;
            }
        }
    }
#undef LSTM_STEP
}

// ---------------- gate GEMM + blend epilogue ----------------
// gamma = sigmoid([fo|fs] @ gW^T + gb); out = gamma*fo + (1-gamma)*fs
__global__ __launch_bounds__(256) void gemm_gate(
    const u16* __restrict__ gW, const float* __restrict__ gb,
    const float* __restrict__ fo, const float* __restrict__ fs,
    float* __restrict__ out)
{
    __shared__ __align__(16) u16 Asm[128*32];
    __shared__ __align__(16) u16 Bsm[128*32];
    const int m0 = blockIdx.x * 128, n0 = blockIdx.y * 128;
    const int tid = threadIdx.x;
    const int ar = tid >> 2, ch = (tid & 3) * 8;
    const float* af0 = fo + (size_t)(m0 + ar) * 256 + ch;
    const float* af1 = fo + (size_t)(m0 + 64 + ar) * 256 + ch;
    const float* as0 = fs + (size_t)(m0 + ar) * 256 + ch;
    const float* as1 = fs + (size_t)(m0 + 64 + ar) * 256 + ch;
    const u16* bp0 = gW + (size_t)(n0 + ar) * 512 + ch;
    const u16* bp1 = gW + (size_t)(n0 + 64 + ar) * 512 + ch;
    const int lane = tid & 63, wave = tid >> 6;
    const int wm = (wave >> 1) * 64, wn = (wave & 1) * 64;
    const int qr = lane >> 4, lr = lane & 15;
    f32x4 acc[4][4] = {};
    for (int k0 = 0; k0 < 512; k0 += 32){
        __syncthreads();
        const float* s0 = (k0 < 256) ? (af0 + k0) : (as0 + (k0 - 256));
        const float* s1 = (k0 < 256) ? (af1 + k0) : (as1 + (k0 - 256));
        float4 x0 = ((const float4*)s0)[0], x1 = ((const float4*)s0)[1];
        float4 y0 = ((const float4*)s1)[0], y1 = ((const float4*)s1)[1];
        ushort4 a0; a0.x=f2b(x0.x); a0.y=f2b(x0.y); a0.z=f2b(x0.z); a0.w=f2b(x0.w);
        ushort4 a1; a1.x=f2b(x1.x); a1.y=f2b(x1.y); a1.z=f2b(x1.z); a1.w=f2b(x1.w);
        ushort4 b0; b0.x=f2b(y0.x); b0.y=f2b(y0.y); b0.z=f2b(y0.z); b0.w=f2b(y0.w);
        ushort4 b1; b1.x=f2b(y1.x); b1.y=f2b(y1.y); b1.z=f2b(y1.z); b1.w=f2b(y1.w);
        *(ushort4*)&Asm[ar*32 + ch]          = a0;
        *(ushort4*)&Asm[ar*32 + ch + 4]      = a1;
        *(ushort4*)&Asm[(64+ar)*32 + ch]     = b0;
        *(ushort4*)&Asm[(64+ar)*32 + ch + 4] = b1;
        *(short8*)&Bsm[ar*32 + ch]      = *(const short8*)(bp0 + k0);
        *(short8*)&Bsm[(64+ar)*32 + ch] = *(const short8*)(bp1 + k0);
        __syncthreads();
        short8 af[4], bfr[4];
        #pragma unroll
        for (int i = 0; i < 4; ++i){
            af[i]  = *(const short8*)&Asm[(wm + i*16 + lr)*32 + qr*8];
            bfr[i] = *(const short8*)&Bsm[(wn + i*16 + lr)*32 + qr*8];
        }
        #pragma unroll
        for (int i = 0; i < 4; ++i)
            #pragma unroll
            for (int j = 0; j < 4; ++j)
                acc[i][j] = __builtin_amdgcn_mfma_f32_16x16x32_bf16(af[i], bfr[j], acc[i][j], 0, 0, 0);
    }
    #pragma unroll
    for (int j = 0; j < 4; ++j){
        int col = n0 + wn + j*16 + lr;   // 0..255
        float bias = gb[col];
        #pragma unroll
        for (int i = 0; i < 4; ++i){
            #pragma unroll
            for (int r = 0; r < 4; ++r){
                int row = m0 + wm + i*16 + qr*4 + r;
                size_t o = (size_t)row*256 + col;
                float gamma = sigm(acc[i][j][r] + bias);
                out[o] = gamma * fo[o] + (1.f - gamma) * fs[o];
            }
        }
    }
}

extern "C" void kernel_launch(void* const* d_in, const int* in_sizes, int n_in,
                              void* d_out, int out_size, void* d_ws, size_t ws_size,
                              hipStream_t stream)
{
    (void)in_sizes; (void)n_in; (void)out_size; (void)ws_size;
    const int*   wordTok = (const int*)d_in[0];
    const int*   sentTok = (const int*)d_in[1];
    const float* E       = (const float*)d_in[3];
    const float* WihWf   = (const float*)d_in[4];
    const float* WhhWf   = (const float*)d_in[5];
    const float* bWf     = (const float*)d_in[6];
    const float* WihWb   = (const float*)d_in[7];
    const float* WhhWb   = (const float*)d_in[8];
    const float* bWb     = (const float*)d_in[9];
    const float* WihSf   = (const float*)d_in[10];
    const float* WhhSf   = (const float*)d_in[11];
    const float* bSf     = (const float*)d_in[12];
    const float* WihSb   = (const float*)d_in[13];
    const float* WhhSb   = (const float*)d_in[14];
    const float* bSb     = (const float*)d_in[15];
    const float* gateW   = (const float*)d_in[16];
    const float* gateB   = (const float*)d_in[17];
    float* out = (float*)d_out;

    char* w = (char*)d_ws;
    u16* Eb   = (u16*)w;  w += (size_t)30522*768*2;
    u16* Ww   = (u16*)w;  w += (size_t)1024*768*2;
    u16* Ws_  = (u16*)w;  w += (size_t)1024*768*2;
    u16* gWb  = (u16*)w;  w += (size_t)256*512*2;
    u16* preW = (u16*)w;  w += (size_t)32768*1024*2;
    u16* preS = (u16*)w;  w += (size_t)32768*1024*2;
    float* fo = (float*)w; w += (size_t)32768*256*4;
    float* fs = (float*)w; w += (size_t)32768*256*4;
    u16* Whp  = (u16*)w;  w += (size_t)4*512*128*2;

    const int nE4 = 30522*768/4;
    cvt_bf16<<<(nE4+255)/256, 256, 0, stream>>>(E, Eb, nE4);
    cvt_wih_perm<<<512, 192, 0, stream>>>(WihWf, Ww);
    cvt_wih_perm<<<512, 192, 0, stream>>>(WihWb, Ww + 512*768);
    cvt_wih_perm<<<512, 192, 0, stream>>>(WihSf, Ws_);
    cvt_wih_perm<<<512, 192, 0, stream>>>(WihSb, Ws_ + 512*768);
    const int nG4 = 256*512/4;
    cvt_bf16<<<(nG4+255)/256, 256, 0, stream>>>(gateW, gWb, nG4);
    cvt_whh_perm<<<64, 256, 0, stream>>>(WhhWf, Whp);
    cvt_whh_perm<<<64, 256, 0, stream>>>(WhhWb, Whp + 512*128);
    cvt_whh_perm<<<64, 256, 0, stream>>>(WhhSf, Whp + 2*512*128);
    cvt_whh_perm<<<64, 256, 0, stream>>>(WhhSb, Whp + 3*512*128);

    gemm_embed<<<dim3(256,8), 256, 0, stream>>>(Eb, wordTok, Ww, bWf, bWb, preW, 0);
    gemm_embed<<<dim3(256,8), 256, 0, stream>>>(Eb, sentTok, Ws_, bSf, bSb, preS, 1);
    lstm_rec<<<68, 1024, 0, stream>>>(preW, preS, Whp, fo, fs);
    gemm_gate<<<dim3(256,2), 256, 0, stream>>>(gWb, gateB, fo, fs, out);
}

// Round 8
// 1131.758 us; speedup vs baseline: 3.0149x; 1.7074x over previous
//
#include <hip/hip_runtime.h>

typedef unsigned short u16;
typedef __attribute__((ext_vector_type(8))) short short8;
typedef __attribute__((ext_vector_type(4))) float f32x4;

__device__ __forceinline__ u16 f2b(float f){
    unsigned u = __builtin_bit_cast(unsigned, f);
    u += 0x7fffu + ((u >> 16) & 1u);   // RNE
    return (u16)(u >> 16);
}
__device__ __forceinline__ float b2f(u16 s){
    unsigned u = ((unsigned)s) << 16;
    return __builtin_bit_cast(float, u);
}
__device__ __forceinline__ float sigm(float x){ return 1.f/(1.f + __expf(-x)); }
// branch-free tanh: 1 - 2/(1+e^{2x})
__device__ __forceinline__ float tanhf2(float x){
    float e = __expf(2.f * x);
    return 1.f - 2.f/(1.f + e);
}

// ---------------- fp32 -> bf16 conversion ----------------
__global__ __launch_bounds__(256) void cvt_bf16(const float* __restrict__ s,
                                                u16* __restrict__ d, int n4){
    int i = blockIdx.x*256 + threadIdx.x;
    if (i < n4){
        float4 v = ((const float4*)s)[i];
        ushort4 o;
        o.x = f2b(v.x); o.y = f2b(v.y); o.z = f2b(v.z); o.w = f2b(v.w);
        ((ushort4*)d)[i] = o;
    }
}

// ---- W_ih cvt with row permutation: out row (unit*4+gate) = in row (gate*128+unit) ----
__global__ __launch_bounds__(192) void cvt_wih_perm(const float* __restrict__ s,
                                                    u16* __restrict__ d){
    int r = blockIdx.x;               // 0..511 input row
    int j = threadIdx.x;              // 0..191 float4 within row
    int g = r >> 7, u = r & 127;
    int ro = u * 4 + g;
    float4 v = ((const float4*)(s + (size_t)r * 768))[j];
    ushort4 o;
    o.x = f2b(v.x); o.y = f2b(v.y); o.z = f2b(v.z); o.w = f2b(v.w);
    ((ushort4*)(d + (size_t)ro * 768))[j] = o;
}

// ---- W_hh cvt with the same row permutation, 128 cols, bf16 out ----
__global__ __launch_bounds__(256) void cvt_whh_perm(const float* __restrict__ s,
                                                    u16* __restrict__ d){
    int idx = blockIdx.x*256 + threadIdx.x;   // 0..16383
    if (idx >= 512*32) return;
    int r = idx >> 5, j = idx & 31;           // row, float4 within row
    int g = r >> 7, u = r & 127;
    int ro = u * 4 + g;
    float4 v = ((const float4*)(s + (size_t)r * 128))[j];
    ushort4 o;
    o.x = f2b(v.x); o.y = f2b(v.y); o.z = f2b(v.z); o.w = f2b(v.w);
    ((ushort4*)(d + (size_t)ro * 128))[j] = o;
}

// ---------------- embedding-gather + input projection GEMM ----------------
// pre written in the LANE-EXACT layout of the C=4 lstm_rec:
//   idx = ((blk*Tdim + t)*512 + wL*64 + cL*16 + uL)*4 + gate   (u16 units)
// where unit uu = wL*16 + uL, chain-in-block cL, gate 0..3.
// word: blk = dir*8  + (batch>>2), cL = batch&3, Tdim=1024
// sent: blk = dir*128 + (sent>>2), cL = sent&3,  Tdim=64
__global__ __launch_bounds__(256) void gemm_embed(
    const u16* __restrict__ E, const int* __restrict__ tok,
    const u16* __restrict__ Wt, const float* __restrict__ bf_,
    const float* __restrict__ bb_, u16* __restrict__ pre, int sentMode)
{
    __shared__ __align__(16) u16 Asm[128*32];
    __shared__ __align__(16) u16 Bsm[128*32];
    const int m0 = blockIdx.x * 128, n0 = blockIdx.y * 128;
    const int tid = threadIdx.x;
    const int ar = tid >> 2, ch = (tid & 3) * 8;
    const u16* ap0 = E + (size_t)tok[m0 + ar] * 768 + ch;
    const u16* ap1 = E + (size_t)tok[m0 + 64 + ar] * 768 + ch;
    const u16* bp0 = Wt + (size_t)(n0 + ar) * 768 + ch;
    const u16* bp1 = Wt + (size_t)(n0 + 64 + ar) * 768 + ch;
    const int lane = tid & 63, wave = tid >> 6;
    const int wm = (wave >> 1) * 64, wn = (wave & 1) * 64;
    const int qr = lane >> 4, lr = lane & 15;
    f32x4 acc[4][4] = {};
    for (int k0 = 0; k0 < 768; k0 += 32){
        __syncthreads();
        *(short8*)&Asm[ar*32 + ch]      = *(const short8*)(ap0 + k0);
        *(short8*)&Asm[(64+ar)*32 + ch] = *(const short8*)(ap1 + k0);
        *(short8*)&Bsm[ar*32 + ch]      = *(const short8*)(bp0 + k0);
        *(short8*)&Bsm[(64+ar)*32 + ch] = *(const short8*)(bp1 + k0);
        __syncthreads();
        short8 af[4], bfr[4];
        #pragma unroll
        for (int i = 0; i < 4; ++i){
            af[i]  = *(const short8*)&Asm[(wm + i*16 + lr)*32 + qr*8];
            bfr[i] = *(const short8*)&Bsm[(wn + i*16 + lr)*32 + qr*8];
        }
        #pragma unroll
        for (int i = 0; i < 4; ++i)
            #pragma unroll
            for (int j = 0; j < 4; ++j)
                acc[i][j] = __builtin_amdgcn_mfma_f32_16x16x32_bf16(af[i], bfr[j], acc[i][j], 0, 0, 0);
    }
    #pragma unroll
    for (int j = 0; j < 4; ++j){
        int col = n0 + wn + j*16 + lr;
        int dirO = col >> 9, pcol = col & 511;
        int uu = pcol >> 2, gg = pcol & 3;
        float bias = (dirO ? bb_ : bf_)[gg*128 + uu];
        int wL = uu >> 4, uL = uu & 15;
        #pragma unroll
        for (int i = 0; i < 4; ++i){
            #pragma unroll
            for (int r = 0; r < 4; ++r){
                int mrow = m0 + wm + i*16 + qr*4 + r;
                int blk, t, cL, Tdim;
                if (sentMode){ int s = mrow >> 6;  t = mrow & 63;   blk = (dirO<<7) + (s >> 2); cL = s & 3; Tdim = 64; }
                else         { int b = mrow >> 10; t = mrow & 1023; blk = (dirO<<3) + (b >> 2); cL = b & 3; Tdim = 1024; }
                size_t idx = (((size_t)blk * Tdim + t) * 512 + (wL*64 + cL*16 + uL)) * 4 + gg;
                pre[idx] = f2b(acc[i][j][r] + bias);
            }
        }
    }
}

// ---------------- batched MFMA LSTM recurrence (C=4 chains/block) ----------------
// ROUND-8: the r0-r6 invariant ~3.5k-cyc/step floor was MULTI-PIPE SATURATION of
// only 4 active CUs (trans ~640 cyc/SIMD + LDS ~1340 cyc/CU + VALU + MFMA,
// serialized by barrier lockstep). Trans/VALU cost is per WAVE-INSTRUCTION, so
// the lever is MORE CUs at full lane efficiency:
//   - 4 chains per block: word = 16 blocks, sent = 256 blocks (was 4 + 64).
//   - 512 threads = 8 waves; wave owns 64 gate-rows: aw[4][4] pinned (r6 pattern).
//   - MFMA C[512 x 16] has valid cols 0..3 only -> WAVE-LOCAL redistribution of
//     the f32 gate quads through XOR-swizzled LDS (4 masked ds_write_b128 +
//     1 ds_read_b128, no barrier) so EVERY lane owns one (unit,chain) cell:
//     10 trans-instr/wave/step instead of 40.
//   - pre (bias included) added post-redistribution in the gate lane.
//   - h stored DIRECTLY to global (16 lanes x 4B contiguous = 64B chunks);
//     hist buffer + flush deleted.
//   - bare lgkmcnt + s_barrier per step (r5-proven), compiler-visible 4-slot
//     pre prefetch (r5-proven), sched_barrier fences around the barrier.
__global__ __launch_bounds__(512)
__attribute__((amdgpu_waves_per_eu(2)))
void lstm_rec(
    const u16* __restrict__ preW, const u16* __restrict__ preS,
    const u16* __restrict__ Whp,     // [4][512][128] bf16: wordF, wordB, sentF, sentB
    float* __restrict__ fo, float* __restrict__ fs)
{
    const int bg = blockIdx.x;
    const u16* preBlk; const u16* wh; float* out;
    int T, dir, grpb;
    if (bg < 16){                     // word: 8 groups x 2 dirs, T=1024
        dir = bg >> 3; grpb = bg & 7; T = 1024;
        preBlk = preW + (size_t)bg * 1024 * 2048;
        wh = Whp + (size_t)dir*512*128; out = fo;
    } else {                          // sent: 128 groups x 2 dirs, T=64
        int sg = bg - 16; dir = sg >> 7; grpb = sg & 127; T = 64;
        preBlk = preS + (size_t)sg * 64 * 2048;
        wh = Whp + (size_t)(2+dir)*512*128; out = fs;
    }
    const int tid  = threadIdx.x;
    const int w    = tid >> 6, lane = tid & 63;
    const int lr = lane & 15, qr = lane >> 4;
    const int t0 = dir ? (T-1) : 0;
    const int dt = dir ? -1 : 1;

    // A-fragments: 64 W_hh rows per wave, PINNED in VGPRs (r6-proven pattern)
    short8 aw[4][4];
    #pragma unroll
    for (int i = 0; i < 4; ++i)
        #pragma unroll
        for (int kk = 0; kk < 4; ++kk)
            asm volatile("global_load_dwordx4 %0, %1, off"
                         : "=v"(aw[i][kk])
                         : "v"(wh + (size_t)(w*64 + i*16 + lr)*128 + kk*32 + qr*8));
    asm volatile("s_waitcnt vmcnt(0)");
    __builtin_amdgcn_sched_barrier(0);

    __shared__ __align__(16) u16    hb[2][2048];   // bf16 h, [16 cols][128 k], rows 4-15 zero (8KB)
    __shared__ __align__(16) float4 rd[512];       // per-wave gate redistribution (8KB)
    for (int k = tid; k < 4096; k += 512) ((u16*)hb)[k] = 0;

    // gate-lane identity: chain cL = lane>>4 (0..3), unit u = w*16 + (lane&15)
    const int cL = lane >> 4;
    const int ur = lane & 15;
    const int u  = w*16 + ur;
    const int chainG = grpb*4 + cL;
    float* po = out + ((size_t)chainG*T + t0)*256 + dir*128 + u;
    const long ostep = (long)dt * 256;

    // pre prefetch: 4 static slots, compiler-visible (counted vmcnt, r5-proven)
    const long pstep = (long)dt * 2048;
    const u16* p = preBlk + (long)t0 * 2048 + tid*4;
    ushort4 buf[4];
    buf[0] = *(const ushort4*)p;
    buf[1] = *(const ushort4*)(p + pstep);
    buf[2] = *(const ushort4*)(p + 2*pstep);
    p += 3*pstep;

    // LDS addresses
    const int rdW0 = w*64 + lr*16;                 // redist write base (lr = chain, lanes lr<4)
    const int rdR  = w*64 + cL*16 + (ur ^ (cL<<2));// redist read slot
    const int hbW  = cL*128 + (u ^ (cL<<3));       // swizzled hb write (u16 idx)

    float cst = 0.f;
    __syncthreads();

#define LSTM_STEP(J, LOADJ) do {                                              \
    short8 bfr[4];                                                            \
    _Pragma("unroll")                                                         \
    for (int kk = 0; kk < 4; ++kk)                                            \
        bfr[kk] = *(const short8*)&hb[(J)&1][lr*128 + ((((kk)*4+qr) ^ lr)<<3)];\
    buf[LOADJ] = *(const ushort4*)p;                                          \
    p += pstep;                                                               \
    f32x4 acc[4] = {};                                                        \
    _Pragma("unroll")                                                         \
    for (int i = 0; i < 4; ++i)                                               \
        _Pragma("unroll")                                                     \
        for (int kk = 0; kk < 4; ++kk)                                        \
            acc[i] = __builtin_amdgcn_mfma_f32_16x16x32_bf16(aw[i][kk], bfr[kk], acc[i], 0, 0, 0); \
    if (lr < 4){                                                              \
        _Pragma("unroll")                                                     \
        for (int i = 0; i < 4; ++i)                                           \
            rd[rdW0 + ((i*4+qr) ^ (lr<<2))] = __builtin_bit_cast(float4, acc[i]); \
    }                                                                         \
    float4 g4 = rd[rdR];                                                      \
    ushort4 pc = buf[J];                                                      \
    float a0 = b2f(pc.x) + g4.x, a1 = b2f(pc.y) + g4.y;                       \
    float a2 = b2f(pc.z) + g4.z, a3 = b2f(pc.w) + g4.w;                       \
    float gi = sigm(a0), gf = sigm(a1);                                       \
    float gg = tanhf2(a2), go = sigm(a3);                                     \
    float c = gf*cst + gi*gg; cst = c;                                        \
    float h = go*tanhf2(c);                                                   \
    po[0] = h;                                                                \
    po += ostep;                                                              \
    hb[((J)&1)^1][hbW] = f2b(h);                                              \
    __builtin_amdgcn_sched_barrier(0);                                        \
    asm volatile("s_waitcnt lgkmcnt(0)");                                     \
    __builtin_amdgcn_s_barrier();                                             \
    __builtin_amdgcn_sched_barrier(0);                                        \
} while(0)

    for (int itBase = 0; itBase < T; itBase += 4){
        LSTM_STEP(0, 3);
        LSTM_STEP(1, 0);
        LSTM_STEP(2, 1);
        LSTM_STEP(3, 2);
    }
#undef LSTM_STEP
}

// ---------------- gate GEMM + blend epilogue ----------------
// gamma = sigmoid([fo|fs] @ gW^T + gb); out = gamma*fo + (1-gamma)*fs
__global__ __launch_bounds__(256) void gemm_gate(
    const u16* __restrict__ gW, const float* __restrict__ gb,
    const float* __restrict__ fo, const float* __restrict__ fs,
    float* __restrict__ out)
{
    __shared__ __align__(16) u16 Asm[128*32];
    __shared__ __align__(16) u16 Bsm[128*32];
    const int m0 = blockIdx.x * 128, n0 = blockIdx.y * 128;
    const int tid = threadIdx.x;
    const int ar = tid >> 2, ch = (tid & 3) * 8;
    const float* af0 = fo + (size_t)(m0 + ar) * 256 + ch;
    const float* af1 = fo + (size_t)(m0 + 64 + ar) * 256 + ch;
    const float* as0 = fs + (size_t)(m0 + ar) * 256 + ch;
    const float* as1 = fs + (size_t)(m0 + 64 + ar) * 256 + ch;
    const u16* bp0 = gW + (size_t)(n0 + ar) * 512 + ch;
    const u16* bp1 = gW + (size_t)(n0 + 64 + ar) * 512 + ch;
    const int lane = tid & 63, wave = tid >> 6;
    const int wm = (wave >> 1) * 64, wn = (wave & 1) * 64;
    const int qr = lane >> 4, lr = lane & 15;
    f32x4 acc[4][4] = {};
    for (int k0 = 0; k0 < 512; k0 += 32){
        __syncthreads();
        const float* s0 = (k0 < 256) ? (af0 + k0) : (as0 + (k0 - 256));
        const float* s1 = (k0 < 256) ? (af1 + k0) : (as1 + (k0 - 256));
        float4 x0 = ((const float4*)s0)[0], x1 = ((const float4*)s0)[1];
        float4 y0 = ((const float4*)s1)[0], y1 = ((const float4*)s1)[1];
        ushort4 a0; a0.x=f2b(x0.x); a0.y=f2b(x0.y); a0.z=f2b(x0.z); a0.w=f2b(x0.w);
        ushort4 a1; a1.x=f2b(x1.x); a1.y=f2b(x1.y); a1.z=f2b(x1.z); a1.w=f2b(x1.w);
        ushort4 b0; b0.x=f2b(y0.x); b0.y=f2b(y0.y); b0.z=f2b(y0.z); b0.w=f2b(y0.w);
        ushort4 b1; b1.x=f2b(y1.x); b1.y=f2b(y1.y); b1.z=f2b(y1.z); b1.w=f2b(y1.w);
        *(ushort4*)&Asm[ar*32 + ch]          = a0;
        *(ushort4*)&Asm[ar*32 + ch + 4]      = a1;
        *(ushort4*)&Asm[(64+ar)*32 + ch]     = b0;
        *(ushort4*)&Asm[(64+ar)*32 + ch + 4] = b1;
        *(short8*)&Bsm[ar*32 + ch]      = *(const short8*)(bp0 + k0);
        *(short8*)&Bsm[(64+ar)*32 + ch] = *(const short8*)(bp1 + k0);
        __syncthreads();
        short8 af[4], bfr[4];
        #pragma unroll
        for (int i = 0; i < 4; ++i){
            af[i]  = *(const short8*)&Asm[(wm + i*16 + lr)*32 + qr*8];
            bfr[i] = *(const short8*)&Bsm[(wn + i*16 + lr)*32 + qr*8];
        }
        #pragma unroll
        for (int i = 0; i < 4; ++i)
            #pragma unroll
            for (int j = 0; j < 4; ++j)
                acc[i][j] = __builtin_amdgcn_mfma_f32_16x16x32_bf16(af[i], bfr[j], acc[i][j], 0, 0, 0);
    }
    #pragma unroll
    for (int j = 0; j < 4; ++j){
        int col = n0 + wn + j*16 + lr;   // 0..255
        float bias = gb[col];
        #pragma unroll
        for (int i = 0; i < 4; ++i){
            #pragma unroll
            for (int r = 0; r < 4; ++r){
                int row = m0 + wm + i*16 + qr*4 + r;
                size_t o = (size_t)row*256 + col;
                float gamma = sigm(acc[i][j][r] + bias);
                out[o] = gamma * fo[o] + (1.f - gamma) * fs[o];
            }
        }
    }
}

extern "C" void kernel_launch(void* const* d_in, const int* in_sizes, int n_in,
                              void* d_out, int out_size, void* d_ws, size_t ws_size,
                              hipStream_t stream)
{
    (void)in_sizes; (void)n_in; (void)out_size; (void)ws_size;
    const int*   wordTok = (const int*)d_in[0];
    const int*   sentTok = (const int*)d_in[1];
    const float* E       = (const float*)d_in[3];
    const float* WihWf   = (const float*)d_in[4];
    const float* WhhWf   = (const float*)d_in[5];
    const float* bWf     = (const float*)d_in[6];
    const float* WihWb   = (const float*)d_in[7];
    const float* WhhWb   = (const float*)d_in[8];
    const float* bWb     = (const float*)d_in[9];
    const float* WihSf   = (const float*)d_in[10];
    const float* WhhSf   = (const float*)d_in[11];
    const float* bSf     = (const float*)d_in[12];
    const float* WihSb   = (const float*)d_in[13];
    const float* WhhSb   = (const float*)d_in[14];
    const float* bSb     = (const float*)d_in[15];
    const float* gateW   = (const float*)d_in[16];
    const float* gateB   = (const float*)d_in[17];
    float* out = (float*)d_out;

    char* w = (char*)d_ws;
    u16* Eb   = (u16*)w;  w += (size_t)30522*768*2;
    u16* Ww   = (u16*)w;  w += (size_t)1024*768*2;
    u16* Ws_  = (u16*)w;  w += (size_t)1024*768*2;
    u16* gWb  = (u16*)w;  w += (size_t)256*512*2;
    u16* preW = (u16*)w;  w += (size_t)32768*1024*2;
    u16* preS = (u16*)w;  w += (size_t)32768*1024*2;
    float* fo = (float*)w; w += (size_t)32768*256*4;
    float* fs = (float*)w; w += (size_t)32768*256*4;
    u16* Whp  = (u16*)w;  w += (size_t)4*512*128*2;

    const int nE4 = 30522*768/4;
    cvt_bf16<<<(nE4+255)/256, 256, 0, stream>>>(E, Eb, nE4);
    cvt_wih_perm<<<512, 192, 0, stream>>>(WihWf, Ww);
    cvt_wih_perm<<<512, 192, 0, stream>>>(WihWb, Ww + 512*768);
    cvt_wih_perm<<<512, 192, 0, stream>>>(WihSf, Ws_);
    cvt_wih_perm<<<512, 192, 0, stream>>>(WihSb, Ws_ + 512*768);
    const int nG4 = 256*512/4;
    cvt_bf16<<<(nG4+255)/256, 256, 0, stream>>>(gateW, gWb, nG4);
    cvt_whh_perm<<<64, 256, 0, stream>>>(WhhWf, Whp);
    cvt_whh_perm<<<64, 256, 0, stream>>>(WhhWb, Whp + 512*128);
    cvt_whh_perm<<<64, 256, 0, stream>>>(WhhSf, Whp + 2*512*128);
    cvt_whh_perm<<<64, 256, 0, stream>>>(WhhSb, Whp + 3*512*128);

    gemm_embed<<<dim3(256,8), 256, 0, stream>>>(Eb, wordTok, Ww, bWf, bWb, preW, 0);
    gemm_embed<<<dim3(256,8), 256, 0, stream>>>(Eb, sentTok, Ws_, bSf, bSb, preS, 1);
    lstm_rec<<<272, 512, 0, stream>>>(preW, preS, Whp, fo, fs);
    gemm_gate<<<dim3(256,2), 256, 0, stream>>>(gWb, gateB, fo, fs, out);
}